// Round 8
// baseline (463.161 us; speedup 1.0000x reference)
//
#include <hip/hip_runtime.h>
#include <cstdint>
#include <cstddef>

// Shapes (fixed): B=64, N=4, P=128, d=h=256, totP=512, feat=131072
#define P_    128
#define H_    256
#define FEAT_ 131072

// ---------------------------------------------------------------------------
// xn: row-normalize x. 8192 blocks x 256 thr; one wave per row, float4 loads,
// wave-shuffle reduce.
// ---------------------------------------------------------------------------
__global__ __launch_bounds__(256) void k_xn(
    const float* __restrict__ x, float* __restrict__ xn) {
  const int t = threadIdx.x;
  const int lane = t & 63;
  const int row = blockIdx.x * 4 + (t >> 6);
  const float* xr = x + (size_t)row * 256;
  const float4 v = *(const float4*)(xr + lane * 4);
  float ss = v.x * v.x + v.y * v.y + v.z * v.z + v.w * v.w;
  #pragma unroll
  for (int s = 32; s; s >>= 1) ss += __shfl_xor(ss, s, 64);
  const float inv = 1.0f / fmaxf(sqrtf(ss), 1e-12f);
  *(float4*)(xn + (size_t)row * 256 + lane * 4) =
      make_float4(v.x * inv, v.y * inv, v.z * inv, v.w * inv);
}

// ---------------------------------------------------------------------------
// Fused sim + deg + sym-normalize. One block per blk (256 blocks, 256 thr).
// ---------------------------------------------------------------------------
__global__ __launch_bounds__(256) void k_simfused(
    const float* __restrict__ xn, const float* __restrict__ mask,
    float* __restrict__ An) {
  __shared__ float Xs[16][128];      // [k][row], chunk of K
  __shared__ float red[128][17];     // row partial sums
  __shared__ float dinv_s[128];
  const int blk = blockIdx.x;
  const int t = threadIdx.x;
  const int tp = t >> 4, tq = t & 15;   // rows tp*8..+7, cols tq*8..+7
  const float* Xb = xn + (size_t)blk * (128 * 256);

  float v[8][8];
  #pragma unroll
  for (int i = 0; i < 8; ++i)
    #pragma unroll
    for (int j = 0; j < 8; ++j) v[i][j] = 0.f;

  for (int kc = 0; kc < 16; ++kc) {
    __syncthreads();
    #pragma unroll
    for (int l = 0; l < 2; ++l) {
      const int f = t + 256 * l;
      const int row = f >> 2, k4 = (f & 3) * 4;
      const float4 x4 = *(const float4*)(Xb + (size_t)row * 256 + kc * 16 + k4);
      Xs[k4 + 0][row] = x4.x;
      Xs[k4 + 1][row] = x4.y;
      Xs[k4 + 2][row] = x4.z;
      Xs[k4 + 3][row] = x4.w;
    }
    __syncthreads();
    #pragma unroll
    for (int k = 0; k < 16; ++k) {
      const float4 a0 = *(const float4*)&Xs[k][tp * 8];
      const float4 a1 = *(const float4*)&Xs[k][tp * 8 + 4];
      const float4 b0 = *(const float4*)&Xs[k][tq * 8];
      const float4 b1 = *(const float4*)&Xs[k][tq * 8 + 4];
      const float a[8] = {a0.x, a0.y, a0.z, a0.w, a1.x, a1.y, a1.z, a1.w};
      const float b[8] = {b0.x, b0.y, b0.z, b0.w, b1.x, b1.y, b1.z, b1.w};
      #pragma unroll
      for (int i = 0; i < 8; ++i)
        #pragma unroll
        for (int j = 0; j < 8; ++j) v[i][j] += a[i] * b[j];
    }
  }

  #pragma unroll
  for (int i = 0; i < 8; ++i) {
    const int r = tp * 8 + i;
    const float4 m0 = *(const float4*)(mask + r * 128 + tq * 8);
    const float4 m1 = *(const float4*)(mask + r * 128 + tq * 8 + 4);
    const float mm[8] = {m0.x, m0.y, m0.z, m0.w, m1.x, m1.y, m1.z, m1.w};
    float s = 0.f;
    #pragma unroll
    for (int j = 0; j < 8; ++j) {
      const int c = tq * 8 + j;
      const float vv = (r == c) ? 0.0f : (v[i][j] + 1.0f) * 0.5f * mm[j];
      v[i][j] = vv;
      s += vv;
    }
    red[r][tq] = s;
  }
  __syncthreads();
  if (t < 128) {
    float sm = 0.f;
    #pragma unroll
    for (int u = 0; u < 16; ++u) sm += red[t][u];
    const float deg = 1.0f + sm;
    dinv_s[t] = (deg > 0.0f) ? rsqrtf(fmaxf(deg, 1e-12f)) : 0.0f;
  }
  __syncthreads();

  float dq[8];
  #pragma unroll
  for (int j = 0; j < 8; ++j) dq[j] = dinv_s[tq * 8 + j];
  float* Ab = An + (size_t)blk * 16384;
  #pragma unroll
  for (int i = 0; i < 8; ++i) {
    const int r = tp * 8 + i;
    const float dp = dinv_s[r];
    float o[8];
    #pragma unroll
    for (int j = 0; j < 8; ++j) {
      const int c = tq * 8 + j;
      o[j] = (r == c) ? dp * dq[j] : v[i][j] * dp * dq[j];
    }
    *(float4*)(Ab + (size_t)r * 128 + tq * 8)     = make_float4(o[0], o[1], o[2], o[3]);
    *(float4*)(Ab + (size_t)r * 128 + tq * 8 + 4) = make_float4(o[4], o[5], o[6], o[7]);
  }
}

// ---------------------------------------------------------------------------
// GEMM (layer 1): out[32768][256] = A @ W + bias.
// 64x64 tile, ONE WAVE per block (64 thr), grid (512,4) = 2048 blocks
// (8 blocks/CU). 8x8 per thread; fragments split tp*4 / 32+tp*4 and
// tq*4 / 32+tq*4; LDS padded [16][68] -> conflict-free b128 reads.
// Bias-first + ascending-k FMA: per-element math identical to prior rounds.
// ---------------------------------------------------------------------------
__global__ __launch_bounds__(64) void k_gemm_t(
    const float* __restrict__ A, const float* __restrict__ W,
    const float* __restrict__ bias, float* __restrict__ out) {
  __shared__ float As[16][68];   // [k][row], pad 68 keeps 16B align + even banks
  __shared__ float Ws[16][68];   // [k][col]
  const int t = threadIdx.x, tp = t >> 3, tq = t & 7;
  const int m0 = blockIdx.x * 64, c0 = blockIdx.y * 64;

  float acc[8][8];
  #pragma unroll
  for (int j = 0; j < 8; ++j) {
    const int cj = (j < 4) ? (tq * 4 + j) : (32 + tq * 4 + (j - 4));
    const float bj = bias[c0 + cj];
    #pragma unroll
    for (int i = 0; i < 8; ++i) acc[i][j] = bj;
  }

  for (int kc = 0; kc < 16; ++kc) {
    float4 ra[4], rw[4];
    #pragma unroll
    for (int l = 0; l < 4; ++l) {
      ra[l] = *(const float4*)(A + (size_t)(m0 + l * 16 + (t >> 2)) * 256 +
                               kc * 16 + (t & 3) * 4);
      rw[l] = *(const float4*)(W + (size_t)(kc * 16 + l * 4 + (t >> 4)) * 256 +
                               c0 + (t & 15) * 4);
    }
    __syncthreads();   // 1-wave: cheap; guards WAR on LDS
    #pragma unroll
    for (int l = 0; l < 4; ++l) {
      const int row = l * 16 + (t >> 2), k4 = (t & 3) * 4;
      As[k4 + 0][row] = ra[l].x; As[k4 + 1][row] = ra[l].y;
      As[k4 + 2][row] = ra[l].z; As[k4 + 3][row] = ra[l].w;
      *(float4*)&Ws[l * 4 + (t >> 4)][(t & 15) * 4] = rw[l];
    }
    __syncthreads();
    #pragma unroll
    for (int k = 0; k < 16; ++k) {
      const float4 a0 = *(const float4*)&As[k][tp * 4];
      const float4 a1 = *(const float4*)&As[k][32 + tp * 4];
      const float4 w0 = *(const float4*)&Ws[k][tq * 4];
      const float4 w1 = *(const float4*)&Ws[k][32 + tq * 4];
      const float a[8] = {a0.x, a0.y, a0.z, a0.w, a1.x, a1.y, a1.z, a1.w};
      const float w[8] = {w0.x, w0.y, w0.z, w0.w, w1.x, w1.y, w1.z, w1.w};
      #pragma unroll
      for (int i = 0; i < 8; ++i)
        #pragma unroll
        for (int j = 0; j < 8; ++j) acc[i][j] += a[i] * w[j];
    }
  }

  #pragma unroll
  for (int i = 0; i < 8; ++i) {
    const int ri = (i < 4) ? (tp * 4 + i) : (32 + tp * 4 + (i - 4));
    float* orow = out + (size_t)(m0 + ri) * 256 + c0;
    *(float4*)(orow + tq * 4)      = make_float4(acc[i][0], acc[i][1], acc[i][2], acc[i][3]);
    *(float4*)(orow + 32 + tq * 4) = make_float4(acc[i][4], acc[i][5], acc[i][6], acc[i][7]);
  }
}

// ---------------------------------------------------------------------------
// GEMM (layer 2), same 64x64 1-wave structure, fused BN+ReLU on A staging.
// scsh: [0..255]=sc, [256..511]=sh; channel = k index.
// ---------------------------------------------------------------------------
__global__ __launch_bounds__(64) void k_gemmbn_t(
    const float* __restrict__ A, const float* __restrict__ scsh,
    const float* __restrict__ W, const float* __restrict__ bias,
    float* __restrict__ out) {
  __shared__ float As[16][68];
  __shared__ float Ws[16][68];
  const int t = threadIdx.x, tp = t >> 3, tq = t & 7;
  const int m0 = blockIdx.x * 64, c0 = blockIdx.y * 64;

  float acc[8][8];
  #pragma unroll
  for (int j = 0; j < 8; ++j) {
    const int cj = (j < 4) ? (tq * 4 + j) : (32 + tq * 4 + (j - 4));
    const float bj = bias[c0 + cj];
    #pragma unroll
    for (int i = 0; i < 8; ++i) acc[i][j] = bj;
  }

  for (int kc = 0; kc < 16; ++kc) {
    float4 ra[4], rw[4];
    const int col = kc * 16 + (t & 3) * 4;               // channel of h1
    const float4 sc = *(const float4*)(scsh + col);
    const float4 sh = *(const float4*)(scsh + 256 + col);
    #pragma unroll
    for (int l = 0; l < 4; ++l) {
      const float4 p = *(const float4*)(A + (size_t)(m0 + l * 16 + (t >> 2)) * 256 + col);
      ra[l].x = fmaxf(p.x * sc.x + sh.x, 0.0f);
      ra[l].y = fmaxf(p.y * sc.y + sh.y, 0.0f);
      ra[l].z = fmaxf(p.z * sc.z + sh.z, 0.0f);
      ra[l].w = fmaxf(p.w * sc.w + sh.w, 0.0f);
      rw[l] = *(const float4*)(W + (size_t)(kc * 16 + l * 4 + (t >> 4)) * 256 +
                               c0 + (t & 15) * 4);
    }
    __syncthreads();
    #pragma unroll
    for (int l = 0; l < 4; ++l) {
      const int row = l * 16 + (t >> 2), k4 = (t & 3) * 4;
      As[k4 + 0][row] = ra[l].x; As[k4 + 1][row] = ra[l].y;
      As[k4 + 2][row] = ra[l].z; As[k4 + 3][row] = ra[l].w;
      *(float4*)&Ws[l * 4 + (t >> 4)][(t & 15) * 4] = rw[l];
    }
    __syncthreads();
    #pragma unroll
    for (int k = 0; k < 16; ++k) {
      const float4 a0 = *(const float4*)&As[k][tp * 4];
      const float4 a1 = *(const float4*)&As[k][32 + tp * 4];
      const float4 w0 = *(const float4*)&Ws[k][tq * 4];
      const float4 w1 = *(const float4*)&Ws[k][32 + tq * 4];
      const float a[8] = {a0.x, a0.y, a0.z, a0.w, a1.x, a1.y, a1.z, a1.w};
      const float w[8] = {w0.x, w0.y, w0.z, w0.w, w1.x, w1.y, w1.z, w1.w};
      #pragma unroll
      for (int i = 0; i < 8; ++i)
        #pragma unroll
        for (int j = 0; j < 8; ++j) acc[i][j] += a[i] * w[j];
    }
  }

  #pragma unroll
  for (int i = 0; i < 8; ++i) {
    const int ri = (i < 4) ? (tp * 4 + i) : (32 + tp * 4 + (i - 4));
    float* orow = out + (size_t)(m0 + ri) * 256 + c0;
    *(float4*)(orow + tq * 4)      = make_float4(acc[i][0], acc[i][1], acc[i][2], acc[i][3]);
    *(float4*)(orow + 32 + tq * 4) = make_float4(acc[i][4], acc[i][5], acc[i][6], acc[i][7]);
  }
}

// ---------------------------------------------------------------------------
// bmm + fused BN-stat partials. 64x64 tile, 1-wave blocks, grid (256, 8):
// y = rh*4 + cq (row-half 0..1, col-quarter 0..3). K=128 (8 chunks).
// Stats: per-block per-col sum/sumsq over its 64 rows ->
// part[(blk*8+y)*128 + {c | 64+c}]. Deterministic fixed order.
// ---------------------------------------------------------------------------
__global__ __launch_bounds__(64) void k_bmmst(
    const float* __restrict__ An, const float* __restrict__ XW,
    float* __restrict__ out, float* __restrict__ part) {
  __shared__ float As[16][68];   // [q][p]
  __shared__ float Ws[16][68];   // [q][c]
  __shared__ float rs[8][64];
  __shared__ float rq[8][64];
  const int blk = blockIdx.x;
  const int y = blockIdx.y;            // 0..7
  const int rh = y >> 2, cq = y & 3;
  const int t = threadIdx.x, tp = t >> 3, tq = t & 7;
  const float* Ab = An + (size_t)blk * 16384 + (size_t)rh * 64 * 128;
  const float* Xb = XW + (size_t)blk * (128 * 256);

  float acc[8][8];
  #pragma unroll
  for (int i = 0; i < 8; ++i)
    #pragma unroll
    for (int j = 0; j < 8; ++j) acc[i][j] = 0.f;

  for (int kc = 0; kc < 8; ++kc) {     // K=128, ascending q
    float4 ra[4], rw[4];
    #pragma unroll
    for (int l = 0; l < 4; ++l) {
      ra[l] = *(const float4*)(Ab + (size_t)(l * 16 + (t >> 2)) * 128 +
                               kc * 16 + (t & 3) * 4);
      rw[l] = *(const float4*)(Xb + (size_t)(kc * 16 + l * 4 + (t >> 4)) * 256 +
                               cq * 64 + (t & 15) * 4);
    }
    __syncthreads();
    #pragma unroll
    for (int l = 0; l < 4; ++l) {
      const int row = l * 16 + (t >> 2), k4 = (t & 3) * 4;
      As[k4 + 0][row] = ra[l].x; As[k4 + 1][row] = ra[l].y;
      As[k4 + 2][row] = ra[l].z; As[k4 + 3][row] = ra[l].w;
      *(float4*)&Ws[l * 4 + (t >> 4)][(t & 15) * 4] = rw[l];
    }
    __syncthreads();
    #pragma unroll
    for (int k = 0; k < 16; ++k) {
      const float4 a0 = *(const float4*)&As[k][tp * 4];
      const float4 a1 = *(const float4*)&As[k][32 + tp * 4];
      const float4 w0 = *(const float4*)&Ws[k][tq * 4];
      const float4 w1 = *(const float4*)&Ws[k][32 + tq * 4];
      const float a[8] = {a0.x, a0.y, a0.z, a0.w, a1.x, a1.y, a1.z, a1.w};
      const float w[8] = {w0.x, w0.y, w0.z, w0.w, w1.x, w1.y, w1.z, w1.w};
      #pragma unroll
      for (int i = 0; i < 8; ++i)
        #pragma unroll
        for (int j = 0; j < 8; ++j) acc[i][j] += a[i] * w[j];
    }
  }

  // stats: per-thread col partial over 8 rows -> LDS -> per-col final
  __syncthreads();
  #pragma unroll
  for (int j = 0; j < 8; ++j) {
    const int col = (j < 4) ? (tq * 4 + j) : (32 + tq * 4 + (j - 4));
    float cs = 0.f, cq2 = 0.f;
    #pragma unroll
    for (int i = 0; i < 8; ++i) { cs += acc[i][j]; cq2 += acc[i][j] * acc[i][j]; }
    rs[tp][col] = cs;
    rq[tp][col] = cq2;
  }
  __syncthreads();
  {
    float s = 0.f, q = 0.f;
    #pragma unroll
    for (int u = 0; u < 8; ++u) { s += rs[u][t]; q += rq[u][t]; }
    const int base = (blk * 8 + y) * 128;
    part[base + t]      = s;
    part[base + 64 + t] = q;
  }

  #pragma unroll
  for (int i = 0; i < 8; ++i) {
    const int ri = (i < 4) ? (tp * 4 + i) : (32 + tp * 4 + (i - 4));
    float* orow = out + (size_t)(blk * 128 + rh * 64 + ri) * 256 + cq * 64;
    *(float4*)(orow + tq * 4)      = make_float4(acc[i][0], acc[i][1], acc[i][2], acc[i][3]);
    *(float4*)(orow + 32 + tq * 4) = make_float4(acc[i][4], acc[i][5], acc[i][6], acc[i][7]);
  }
}

// ---------------------------------------------------------------------------
// bn final + scsh: block per channel (256 blocks x 256 thr). Thread u sums
// its blk's two row-halves (fixed order), then LDS tree. Deterministic.
// part layout from k_bmmst: (blk*8 + rh*4 + cq)*128 + {lc | 64+lc}, lc=c&63.
// ---------------------------------------------------------------------------
__global__ __launch_bounds__(256) void k_bnscsh(
    const float* __restrict__ part, const float* __restrict__ g,
    const float* __restrict__ be, float* __restrict__ scsh) {
  __shared__ float ss[256], qq[256];
  const int c = blockIdx.x;
  const int cqi = c >> 6, lc = c & 63;
  const int u = threadIdx.x;           // = blk
  const float* p0 = part + (size_t)(u * 8 + cqi) * 128;        // rh=0
  const float* p1 = part + (size_t)(u * 8 + 4 + cqi) * 128;    // rh=1
  ss[u] = p0[lc] + p1[lc];
  qq[u] = p0[64 + lc] + p1[64 + lc];
  __syncthreads();
  for (int st = 128; st; st >>= 1) {
    if (u < st) { ss[u] += ss[u + st]; qq[u] += qq[u + st]; }
    __syncthreads();
  }
  if (u == 0) {
    const float m = ss[0] * (1.0f / 32768.0f);
    const float var = qq[0] * (1.0f / 32768.0f) - m * m;
    const float sc = g[c] * rsqrtf(var + 1e-5f);
    scsh[c] = sc;
    scsh[256 + c] = be[c] - m * sc;
  }
}

// ---------------------------------------------------------------------------
// head split-K GEMM v3: 1024 blocks (K-chunk 128) x 256 thr. Graph chunk
// staged in LDS with BN+ReLU applied once. Partials -> part (1024 x 8192).
// ---------------------------------------------------------------------------
__global__ __launch_bounds__(256) void k_headgemm_v3(
    const float* __restrict__ pre2, const float* __restrict__ scsh,
    const float* __restrict__ Wm1, float* __restrict__ part) {
  __shared__ float graphS[64][128];   // 32 KB
  const int t = threadIdx.x;
  const int bid = blockIdx.x;
  const int k0 = bid * 128;
  const int cbase = k0 & 255;

  #pragma unroll
  for (int l = 0; l < 8; ++l) {
    const int f = t + 256 * l;
    const int row = f >> 5, c4 = (f & 31) * 4;
    const float4 p = *(const float4*)(pre2 + (size_t)row * FEAT_ + k0 + c4);
    const float4 sc = *(const float4*)(scsh + cbase + c4);
    const float4 sh = *(const float4*)(scsh + 256 + cbase + c4);
    graphS[row][c4 + 0] = fmaxf(p.x * sc.x + sh.x, 0.0f);
    graphS[row][c4 + 1] = fmaxf(p.y * sc.y + sh.y, 0.0f);
    graphS[row][c4 + 2] = fmaxf(p.z * sc.z + sh.z, 0.0f);
    graphS[row][c4 + 3] = fmaxf(p.w * sc.w + sh.w, 0.0f);
  }
  __syncthreads();

  const int hg = t & 31;
  const int bg = t >> 5;
  float acc[8][4];
  #pragma unroll
  for (int i = 0; i < 8; ++i)
    #pragma unroll
    for (int j = 0; j < 4; ++j) acc[i][j] = 0.f;

  #pragma unroll 2
  for (int kk = 0; kk < 128; kk += 4) {
    const int k = k0 + kk;
    const float4 w0 = *(const float4*)(Wm1 + (size_t)(k + 0) * 128 + hg * 4);
    const float4 w1 = *(const float4*)(Wm1 + (size_t)(k + 1) * 128 + hg * 4);
    const float4 w2 = *(const float4*)(Wm1 + (size_t)(k + 2) * 128 + hg * 4);
    const float4 w3 = *(const float4*)(Wm1 + (size_t)(k + 3) * 128 + hg * 4);
    #pragma unroll
    for (int i = 0; i < 8; ++i) {
      const float4 a = *(const float4*)&graphS[bg * 8 + i][kk];
      acc[i][0] += a.x * w0.x; acc[i][1] += a.x * w0.y;
      acc[i][2] += a.x * w0.z; acc[i][3] += a.x * w0.w;
      acc[i][0] += a.y * w1.x; acc[i][1] += a.y * w1.y;
      acc[i][2] += a.y * w1.z; acc[i][3] += a.y * w1.w;
      acc[i][0] += a.z * w2.x; acc[i][1] += a.z * w2.y;
      acc[i][2] += a.z * w2.z; acc[i][3] += a.z * w2.w;
      acc[i][0] += a.w * w3.x; acc[i][1] += a.w * w3.y;
      acc[i][2] += a.w * w3.z; acc[i][3] += a.w * w3.w;
    }
  }

  float* pb = part + (size_t)bid * 8192;
  #pragma unroll
  for (int i = 0; i < 8; ++i)
    *(float4*)(pb + (bg * 8 + i) * 128 + hg * 4) =
        make_float4(acc[i][0], acc[i][1], acc[i][2], acc[i][3]);
}

// ---------------------------------------------------------------------------
// head reduce stage A: part2[jg][o] = sum of 128 consecutive partials.
// ---------------------------------------------------------------------------
__global__ __launch_bounds__(256) void k_headredA(
    const float* __restrict__ part, float* __restrict__ part2) {
  const int o = blockIdx.x * 256 + threadIdx.x;
  const int jg = blockIdx.y;
  const float* base = part + (size_t)jg * 128 * 8192;
  float s = 0.f;
  for (int j = 0; j < 128; ++j) s += base[(size_t)j * 8192 + o];
  part2[(size_t)jg * 8192 + o] = s;
}

// head reduce stage B: z1[o] = sum_{jg<8} part2[jg][o]
__global__ __launch_bounds__(256) void k_headredB(
    const float* __restrict__ part2, float* __restrict__ z1) {
  const int o = blockIdx.x * 256 + threadIdx.x;
  float s = 0.f;
  #pragma unroll
  for (int jg = 0; jg < 8; ++jg) s += part2[(size_t)jg * 8192 + o];
  z1[o] = s;
}

// ---------------------------------------------------------------------------
// head BN over batch (J features) + ReLU
// ---------------------------------------------------------------------------
template <int J>
__global__ __launch_bounds__(64) void k_headbn(
    const float* __restrict__ z, const float* __restrict__ g,
    const float* __restrict__ be, float* __restrict__ zr) {
  __shared__ float rs[64], rs2[64];
  const int j = blockIdx.x, b = threadIdx.x;
  const float v = z[b * J + j];
  rs[b] = v; rs2[b] = v * v; __syncthreads();
  for (int s = 32; s; s >>= 1) {
    if (b < s) { rs[b] += rs[b + s]; rs2[b] += rs2[b + s]; }
    __syncthreads();
  }
  const float m = rs[0] * (1.0f / 64.0f);
  const float var = rs2[0] * (1.0f / 64.0f) - m * m;
  const float sc = g[j] * rsqrtf(var + 1e-5f);
  const float sh = be[j] - m * sc;
  zr[b * J + j] = fmaxf(v * sc + sh, 0.0f);
}

__global__ __launch_bounds__(64) void k_headmm2(
    const float* __restrict__ zr1, const float* __restrict__ Wm2,
    float* __restrict__ z2) {
  const int b = blockIdx.x, j = threadIdx.x;
  float acc = 0.f;
  for (int k = 0; k < 128; ++k) acc += zr1[b * 128 + k] * Wm2[k * 64 + j];
  z2[b * 64 + j] = acc;
}

__global__ __launch_bounds__(128) void k_headout(
    const float* __restrict__ zr2, const float* __restrict__ Wm3,
    const float* __restrict__ bm3, float* __restrict__ out) {
  const int t = threadIdx.x;
  const int b = t >> 1, c = t & 1;
  float s = bm3[c];
  for (int k = 0; k < 64; ++k) s += zr2[b * 64 + k] * Wm3[k * 2 + c];
  out[t] = s;
}

// ---------------------------------------------------------------------------
extern "C" void kernel_launch(void* const* d_in, const int* in_sizes, int n_in,
                              void* d_out, int out_size, void* d_ws, size_t ws_size,
                              hipStream_t stream) {
  (void)in_sizes; (void)n_in; (void)out_size; (void)ws_size;
  const float* x    = (const float*)d_in[0];
  const float* mask = (const float*)d_in[1];
  const float* W1   = (const float*)d_in[2];
  const float* b1   = (const float*)d_in[3];
  const float* g1   = (const float*)d_in[4];
  const float* be1  = (const float*)d_in[5];
  const float* W2   = (const float*)d_in[6];
  const float* b2   = (const float*)d_in[7];
  const float* g2   = (const float*)d_in[8];
  const float* be2  = (const float*)d_in[9];
  const float* Wm1  = (const float*)d_in[10];
  // d_in[11] = bm1 (zeros; cancels under BN)
  const float* gm1  = (const float*)d_in[12];
  const float* bem1 = (const float*)d_in[13];
  const float* Wm2  = (const float*)d_in[14];
  // d_in[15] = bm2 (zeros; cancels under BN)
  const float* gm2  = (const float*)d_in[16];
  const float* bem2 = (const float*)d_in[17];
  const float* Wm3  = (const float*)d_in[18];
  const float* bm3  = (const float*)d_in[19];

  // workspace (floats), same extent as verified previously (117.67 MB)
  float* ws   = (float*)d_ws;
  float* T1   = ws;                 // 8,388,608 : xn -> bn partials
  float* An   = T1 + 8388608;       // 4,194,304 : An -> head part2
  float* T2   = An + 4194304;       // 8,388,608 : XW1 -> XW2 -> head partials
  float* T3   = T2 + 8388608;       // 8,388,608 : pre1 -> pre2
  float* z1   = T3 + 8388608;       // 8,192
  float* dinv = z1 + 8192;          // 32,768 : scsh1 at +0, scsh2 at +512
  float* st1  = dinv + 32768;       // 512 (unused, kept for layout)
  float* st2  = st1 + 512;          // 512 (unused)
  float* zr1  = st2 + 512;          // 8,192
  float* z2   = zr1 + 8192;         // 4,096
  float* zr2  = z2 + 4096;          // 4,096

  float* scsh1 = dinv;
  float* scsh2 = dinv + 512;

  // edges / An (fused: sim + deg + normalize)
  k_xn<<<8192, 256, 0, stream>>>(x, T1);
  k_simfused<<<256, 256, 0, stream>>>(T1, mask, An);

  // layer 1: pre1 = An @ (x@W1+b1); stats fused into bmm
  k_gemm_t<<<dim3(512, 4), 64, 0, stream>>>(x, W1, b1, T2);
  k_bmmst<<<dim3(256, 8), 64, 0, stream>>>(An, T2, T3, T1);   // T1: xn dead
  k_bnscsh<<<256, 256, 0, stream>>>(T1, g1, be1, scsh1);

  // layer 2: pre2 = An @ (relu(bn(pre1))@W2+b2); bn fused into A-staging
  k_gemmbn_t<<<dim3(512, 4), 64, 0, stream>>>(T3, scsh1, W2, b2, T2);
  k_bmmst<<<dim3(256, 8), 64, 0, stream>>>(An, T2, T3, T1);
  k_bnscsh<<<256, 256, 0, stream>>>(T1, g2, be2, scsh2);

  // head: z1 = relu(bn(pre2)) @ Wm1, LDS-staged split-K + 2-stage reduce
  k_headgemm_v3<<<1024, 256, 0, stream>>>(T3, scsh2, Wm1, T2);
  k_headredA<<<dim3(32, 8), 256, 0, stream>>>(T2, An);
  k_headredB<<<32, 256, 0, stream>>>(An, z1);
  k_headbn<128><<<128, 64, 0, stream>>>(z1, gm1, bem1, zr1);
  k_headmm2<<<64, 64, 0, stream>>>(zr1, Wm2, z2);
  k_headbn<64><<<64, 64, 0, stream>>>(z2, gm2, bem2, zr2);
  k_headout<<<1, 128, 0, stream>>>(zr2, Wm3, bm3, (float*)d_out);
}

// Round 9
// 442.548 us; speedup vs baseline: 1.0466x; 1.0466x over previous
//
#include <hip/hip_runtime.h>
#include <cstdint>
#include <cstddef>

// Shapes (fixed): B=64, N=4, P=128, d=h=256, totP=512, feat=131072
#define P_    128
#define H_    256
#define FEAT_ 131072

// ---------------------------------------------------------------------------
// xn: row-normalize x. 8192 blocks x 256 thr; one wave per row, float4 loads,
// wave-shuffle reduce.
// ---------------------------------------------------------------------------
__global__ __launch_bounds__(256) void k_xn(
    const float* __restrict__ x, float* __restrict__ xn) {
  const int t = threadIdx.x;
  const int lane = t & 63;
  const int row = blockIdx.x * 4 + (t >> 6);
  const float* xr = x + (size_t)row * 256;
  const float4 v = *(const float4*)(xr + lane * 4);
  float ss = v.x * v.x + v.y * v.y + v.z * v.z + v.w * v.w;
  #pragma unroll
  for (int s = 32; s; s >>= 1) ss += __shfl_xor(ss, s, 64);
  const float inv = 1.0f / fmaxf(sqrtf(ss), 1e-12f);
  *(float4*)(xn + (size_t)row * 256 + lane * 4) =
      make_float4(v.x * inv, v.y * inv, v.z * inv, v.w * inv);
}

// ---------------------------------------------------------------------------
// Fused sim + deg + sym-normalize. One block per blk (256 blocks, 256 thr).
// ---------------------------------------------------------------------------
__global__ __launch_bounds__(256) void k_simfused(
    const float* __restrict__ xn, const float* __restrict__ mask,
    float* __restrict__ An) {
  __shared__ float Xs[16][128];      // [k][row], chunk of K
  __shared__ float red[128][17];     // row partial sums
  __shared__ float dinv_s[128];
  const int blk = blockIdx.x;
  const int t = threadIdx.x;
  const int tp = t >> 4, tq = t & 15;   // rows tp*8..+7, cols tq*8..+7
  const float* Xb = xn + (size_t)blk * (128 * 256);

  float v[8][8];
  #pragma unroll
  for (int i = 0; i < 8; ++i)
    #pragma unroll
    for (int j = 0; j < 8; ++j) v[i][j] = 0.f;

  for (int kc = 0; kc < 16; ++kc) {
    __syncthreads();
    #pragma unroll
    for (int l = 0; l < 2; ++l) {
      const int f = t + 256 * l;
      const int row = f >> 2, k4 = (f & 3) * 4;
      const float4 x4 = *(const float4*)(Xb + (size_t)row * 256 + kc * 16 + k4);
      Xs[k4 + 0][row] = x4.x;
      Xs[k4 + 1][row] = x4.y;
      Xs[k4 + 2][row] = x4.z;
      Xs[k4 + 3][row] = x4.w;
    }
    __syncthreads();
    #pragma unroll
    for (int k = 0; k < 16; ++k) {
      const float4 a0 = *(const float4*)&Xs[k][tp * 8];
      const float4 a1 = *(const float4*)&Xs[k][tp * 8 + 4];
      const float4 b0 = *(const float4*)&Xs[k][tq * 8];
      const float4 b1 = *(const float4*)&Xs[k][tq * 8 + 4];
      const float a[8] = {a0.x, a0.y, a0.z, a0.w, a1.x, a1.y, a1.z, a1.w};
      const float b[8] = {b0.x, b0.y, b0.z, b0.w, b1.x, b1.y, b1.z, b1.w};
      #pragma unroll
      for (int i = 0; i < 8; ++i)
        #pragma unroll
        for (int j = 0; j < 8; ++j) v[i][j] += a[i] * b[j];
    }
  }

  #pragma unroll
  for (int i = 0; i < 8; ++i) {
    const int r = tp * 8 + i;
    const float4 m0 = *(const float4*)(mask + r * 128 + tq * 8);
    const float4 m1 = *(const float4*)(mask + r * 128 + tq * 8 + 4);
    const float mm[8] = {m0.x, m0.y, m0.z, m0.w, m1.x, m1.y, m1.z, m1.w};
    float s = 0.f;
    #pragma unroll
    for (int j = 0; j < 8; ++j) {
      const int c = tq * 8 + j;
      const float vv = (r == c) ? 0.0f : (v[i][j] + 1.0f) * 0.5f * mm[j];
      v[i][j] = vv;
      s += vv;
    }
    red[r][tq] = s;
  }
  __syncthreads();
  if (t < 128) {
    float sm = 0.f;
    #pragma unroll
    for (int u = 0; u < 16; ++u) sm += red[t][u];
    const float deg = 1.0f + sm;
    dinv_s[t] = (deg > 0.0f) ? rsqrtf(fmaxf(deg, 1e-12f)) : 0.0f;
  }
  __syncthreads();

  float dq[8];
  #pragma unroll
  for (int j = 0; j < 8; ++j) dq[j] = dinv_s[tq * 8 + j];
  float* Ab = An + (size_t)blk * 16384;
  #pragma unroll
  for (int i = 0; i < 8; ++i) {
    const int r = tp * 8 + i;
    const float dp = dinv_s[r];
    float o[8];
    #pragma unroll
    for (int j = 0; j < 8; ++j) {
      const int c = tq * 8 + j;
      o[j] = (r == c) ? dp * dq[j] : v[i][j] * dp * dq[j];
    }
    *(float4*)(Ab + (size_t)r * 128 + tq * 8)     = make_float4(o[0], o[1], o[2], o[3]);
    *(float4*)(Ab + (size_t)r * 128 + tq * 8 + 4) = make_float4(o[4], o[5], o[6], o[7]);
  }
}

// ---------------------------------------------------------------------------
// Tiled GEMM (layer 1): out[32768][256] = A @ W + bias.
// 64x128 tile, grid (512,2), 256 thr, 4x8/thread — R7 structure with
// SOFTWARE PREFETCH: chunk kc+1 global loads issued before computing chunk
// kc, so HBM/L2 latency hides under the FMA stream. Math bit-identical.
// ---------------------------------------------------------------------------
__global__ __launch_bounds__(256) void k_gemm_t(
    const float* __restrict__ A, const float* __restrict__ W,
    const float* __restrict__ bias, float* __restrict__ out) {
  __shared__ float As[16][64];    // [k][row]
  __shared__ float Ws[16][128];   // [k][col]
  const int rb = blockIdx.x, cb = blockIdx.y;
  const int t = threadIdx.x, tp = t >> 4, tq = t & 15;
  const int m0 = rb * 64, c0 = cb * 128;

  const int arow = t >> 2, ak4 = (t & 3) * 4;   // A staging coords
  const int wk0 = t >> 5, wc = (t & 31) * 4;    // W staging (l=0); l=1: k+8

  float acc[4][8];
  #pragma unroll
  for (int j = 0; j < 8; ++j) {
    const int col = c0 + ((j < 4) ? (tq * 4 + j) : (64 + tq * 4 + j - 4));
    const float bj = bias[col];
    #pragma unroll
    for (int i = 0; i < 4; ++i) acc[i][j] = bj;
  }

  // prologue: load chunk 0
  float4 ra  = *(const float4*)(A + (size_t)(m0 + arow) * 256 + ak4);
  float4 rw0 = *(const float4*)(W + (size_t)(wk0)     * 256 + c0 + wc);
  float4 rw1 = *(const float4*)(W + (size_t)(8 + wk0) * 256 + c0 + wc);

  for (int kc = 0; kc < 16; ++kc) {
    __syncthreads();
    As[ak4 + 0][arow] = ra.x;
    As[ak4 + 1][arow] = ra.y;
    As[ak4 + 2][arow] = ra.z;
    As[ak4 + 3][arow] = ra.w;
    *(float4*)&Ws[wk0][wc]     = rw0;
    *(float4*)&Ws[8 + wk0][wc] = rw1;
    __syncthreads();
    if (kc < 15) {   // prefetch next chunk; overlaps compute below
      const int kn = (kc + 1) * 16;
      ra  = *(const float4*)(A + (size_t)(m0 + arow) * 256 + kn + ak4);
      rw0 = *(const float4*)(W + (size_t)(kn + wk0)     * 256 + c0 + wc);
      rw1 = *(const float4*)(W + (size_t)(kn + 8 + wk0) * 256 + c0 + wc);
    }
    #pragma unroll
    for (int k = 0; k < 16; ++k) {
      const float4 av = *(const float4*)&As[k][tp * 4];
      const float4 w0 = *(const float4*)&Ws[k][tq * 4];
      const float4 w1 = *(const float4*)&Ws[k][64 + tq * 4];
      const float a[4] = {av.x, av.y, av.z, av.w};
      const float w[8] = {w0.x, w0.y, w0.z, w0.w, w1.x, w1.y, w1.z, w1.w};
      #pragma unroll
      for (int i = 0; i < 4; ++i)
        #pragma unroll
        for (int j = 0; j < 8; ++j) acc[i][j] += a[i] * w[j];
    }
  }

  #pragma unroll
  for (int i = 0; i < 4; ++i) {
    float* orow = out + (size_t)(m0 + tp * 4 + i) * 256 + c0;
    *(float4*)(orow + tq * 4)      = make_float4(acc[i][0], acc[i][1], acc[i][2], acc[i][3]);
    *(float4*)(orow + 64 + tq * 4) = make_float4(acc[i][4], acc[i][5], acc[i][6], acc[i][7]);
  }
}

// ---------------------------------------------------------------------------
// Tiled GEMM (layer 2), same structure + prefetch, fused BN+ReLU applied to
// the A prefetch registers. scsh: [0..255]=sc, [256..511]=sh.
// ---------------------------------------------------------------------------
__global__ __launch_bounds__(256) void k_gemmbn_t(
    const float* __restrict__ A, const float* __restrict__ scsh,
    const float* __restrict__ W, const float* __restrict__ bias,
    float* __restrict__ out) {
  __shared__ float As[16][64];
  __shared__ float Ws[16][128];
  const int rb = blockIdx.x, cb = blockIdx.y;
  const int t = threadIdx.x, tp = t >> 4, tq = t & 15;
  const int m0 = rb * 64, c0 = cb * 128;

  const int arow = t >> 2, ak4 = (t & 3) * 4;
  const int wk0 = t >> 5, wc = (t & 31) * 4;

  float acc[4][8];
  #pragma unroll
  for (int j = 0; j < 8; ++j) {
    const int col = c0 + ((j < 4) ? (tq * 4 + j) : (64 + tq * 4 + j - 4));
    const float bj = bias[col];
    #pragma unroll
    for (int i = 0; i < 4; ++i) acc[i][j] = bj;
  }

  // prologue: load + BN chunk 0
  float4 ra;
  {
    const float4 p  = *(const float4*)(A + (size_t)(m0 + arow) * 256 + ak4);
    const float4 sc = *(const float4*)(scsh + ak4);
    const float4 sh = *(const float4*)(scsh + 256 + ak4);
    ra.x = fmaxf(p.x * sc.x + sh.x, 0.0f);
    ra.y = fmaxf(p.y * sc.y + sh.y, 0.0f);
    ra.z = fmaxf(p.z * sc.z + sh.z, 0.0f);
    ra.w = fmaxf(p.w * sc.w + sh.w, 0.0f);
  }
  float4 rw0 = *(const float4*)(W + (size_t)(wk0)     * 256 + c0 + wc);
  float4 rw1 = *(const float4*)(W + (size_t)(8 + wk0) * 256 + c0 + wc);

  for (int kc = 0; kc < 16; ++kc) {
    __syncthreads();
    As[ak4 + 0][arow] = ra.x;
    As[ak4 + 1][arow] = ra.y;
    As[ak4 + 2][arow] = ra.z;
    As[ak4 + 3][arow] = ra.w;
    *(float4*)&Ws[wk0][wc]     = rw0;
    *(float4*)&Ws[8 + wk0][wc] = rw1;
    __syncthreads();
    if (kc < 15) {
      const int kn = (kc + 1) * 16;
      const int col = kn + ak4;
      const float4 p  = *(const float4*)(A + (size_t)(m0 + arow) * 256 + col);
      const float4 sc = *(const float4*)(scsh + col);
      const float4 sh = *(const float4*)(scsh + 256 + col);
      ra.x = fmaxf(p.x * sc.x + sh.x, 0.0f);
      ra.y = fmaxf(p.y * sc.y + sh.y, 0.0f);
      ra.z = fmaxf(p.z * sc.z + sh.z, 0.0f);
      ra.w = fmaxf(p.w * sc.w + sh.w, 0.0f);
      rw0 = *(const float4*)(W + (size_t)(kn + wk0)     * 256 + c0 + wc);
      rw1 = *(const float4*)(W + (size_t)(kn + 8 + wk0) * 256 + c0 + wc);
    }
    #pragma unroll
    for (int k = 0; k < 16; ++k) {
      const float4 av = *(const float4*)&As[k][tp * 4];
      const float4 w0 = *(const float4*)&Ws[k][tq * 4];
      const float4 w1 = *(const float4*)&Ws[k][64 + tq * 4];
      const float a[4] = {av.x, av.y, av.z, av.w};
      const float w[8] = {w0.x, w0.y, w0.z, w0.w, w1.x, w1.y, w1.z, w1.w};
      #pragma unroll
      for (int i = 0; i < 4; ++i)
        #pragma unroll
        for (int j = 0; j < 8; ++j) acc[i][j] += a[i] * w[j];
    }
  }

  #pragma unroll
  for (int i = 0; i < 4; ++i) {
    float* orow = out + (size_t)(m0 + tp * 4 + i) * 256 + c0;
    *(float4*)(orow + tq * 4)      = make_float4(acc[i][0], acc[i][1], acc[i][2], acc[i][3]);
    *(float4*)(orow + 64 + tq * 4) = make_float4(acc[i][4], acc[i][5], acc[i][6], acc[i][7]);
  }
}

// ---------------------------------------------------------------------------
// Tiled bmm + fused BN-stat partials, 64x128 tile, grid (256,4), prefetch.
// y = rh*2+cb. part[(blk*4+y)*256 + {c | 128+c}]. Deterministic.
// ---------------------------------------------------------------------------
__global__ __launch_bounds__(256) void k_bmmst(
    const float* __restrict__ An, const float* __restrict__ XW,
    float* __restrict__ out, float* __restrict__ part) {
  __shared__ float As[16][64];    // [q][p]
  __shared__ float Ws[16][128];   // [q][c]
  __shared__ float rs[16][128];
  __shared__ float rq[16][128];
  const int blk = blockIdx.x;
  const int y = blockIdx.y;            // 0..3
  const int rh = y >> 1, cb = y & 1;
  const int t = threadIdx.x, tp = t >> 4, tq = t & 15;
  const float* Ab = An + (size_t)blk * 16384 + (size_t)rh * 64 * 128;
  const float* Xb = XW + (size_t)blk * (128 * 256);

  const int arow = t >> 2, ak4 = (t & 3) * 4;
  const int wk0 = t >> 5, wc = (t & 31) * 4;

  float acc[4][8];
  #pragma unroll
  for (int i = 0; i < 4; ++i)
    #pragma unroll
    for (int j = 0; j < 8; ++j) acc[i][j] = 0.f;

  // prologue: load chunk 0
  float4 ra  = *(const float4*)(Ab + (size_t)arow * 128 + ak4);
  float4 rw0 = *(const float4*)(Xb + (size_t)(wk0)     * 256 + cb * 128 + wc);
  float4 rw1 = *(const float4*)(Xb + (size_t)(8 + wk0) * 256 + cb * 128 + wc);

  for (int kc = 0; kc < 8; ++kc) {     // K=128, ascending q
    __syncthreads();
    As[ak4 + 0][arow] = ra.x;
    As[ak4 + 1][arow] = ra.y;
    As[ak4 + 2][arow] = ra.z;
    As[ak4 + 3][arow] = ra.w;
    *(float4*)&Ws[wk0][wc]     = rw0;
    *(float4*)&Ws[8 + wk0][wc] = rw1;
    __syncthreads();
    if (kc < 7) {
      const int kn = (kc + 1) * 16;
      ra  = *(const float4*)(Ab + (size_t)arow * 128 + kn + ak4);
      rw0 = *(const float4*)(Xb + (size_t)(kn + wk0)     * 256 + cb * 128 + wc);
      rw1 = *(const float4*)(Xb + (size_t)(kn + 8 + wk0) * 256 + cb * 128 + wc);
    }
    #pragma unroll
    for (int k = 0; k < 16; ++k) {
      const float4 av = *(const float4*)&As[k][tp * 4];
      const float4 w0 = *(const float4*)&Ws[k][tq * 4];
      const float4 w1 = *(const float4*)&Ws[k][64 + tq * 4];
      const float a[4] = {av.x, av.y, av.z, av.w};
      const float w[8] = {w0.x, w0.y, w0.z, w0.w, w1.x, w1.y, w1.z, w1.w};
      #pragma unroll
      for (int i = 0; i < 4; ++i)
        #pragma unroll
        for (int j = 0; j < 8; ++j) acc[i][j] += a[i] * w[j];
    }
  }

  // stats: per-thread col partial over 4 rows -> LDS -> 128-thread final
  #pragma unroll
  for (int j = 0; j < 8; ++j) {
    float cs = 0.f, cq = 0.f;
    #pragma unroll
    for (int i = 0; i < 4; ++i) { cs += acc[i][j]; cq += acc[i][j] * acc[i][j]; }
    const int col = (j < 4) ? (tq * 4 + j) : (64 + tq * 4 + j - 4);
    rs[tp][col] = cs;
    rq[tp][col] = cq;
  }
  __syncthreads();
  if (t < 128) {
    float s = 0.f, q = 0.f;
    #pragma unroll
    for (int u = 0; u < 16; ++u) { s += rs[u][t]; q += rq[u][t]; }
    const int base = (blk * 4 + y) * 256;
    part[base + t]       = s;
    part[base + 128 + t] = q;
  }

  #pragma unroll
  for (int i = 0; i < 4; ++i) {
    float* orow = out + (size_t)(blk * 128 + rh * 64 + tp * 4 + i) * 256 + cb * 128;
    *(float4*)(orow + tq * 4)      = make_float4(acc[i][0], acc[i][1], acc[i][2], acc[i][3]);
    *(float4*)(orow + 64 + tq * 4) = make_float4(acc[i][4], acc[i][5], acc[i][6], acc[i][7]);
  }
}

// ---------------------------------------------------------------------------
// bn final + scsh: block per channel (256 blocks x 256 thr). Thread u sums
// its blk's two row-halves (fixed order), then LDS tree. Deterministic.
// ---------------------------------------------------------------------------
__global__ __launch_bounds__(256) void k_bnscsh(
    const float* __restrict__ part, const float* __restrict__ g,
    const float* __restrict__ be, float* __restrict__ scsh) {
  __shared__ float ss[256], qq[256];
  const int c = blockIdx.x;
  const int cb = c >> 7, lc = c & 127;
  const int u = threadIdx.x;           // = blk
  const float* p0 = part + (size_t)(u * 4 + cb) * 256;        // rh=0
  const float* p1 = part + (size_t)(u * 4 + 2 + cb) * 256;    // rh=1
  ss[u] = p0[lc] + p1[lc];
  qq[u] = p0[128 + lc] + p1[128 + lc];
  __syncthreads();
  for (int st = 128; st; st >>= 1) {
    if (u < st) { ss[u] += ss[u + st]; qq[u] += qq[u + st]; }
    __syncthreads();
  }
  if (u == 0) {
    const float m = ss[0] * (1.0f / 32768.0f);
    const float var = qq[0] * (1.0f / 32768.0f) - m * m;
    const float sc = g[c] * rsqrtf(var + 1e-5f);
    scsh[c] = sc;
    scsh[256 + c] = be[c] - m * sc;
  }
}

// ---------------------------------------------------------------------------
// head split-K GEMM v3: 1024 blocks (K-chunk 128) x 256 thr. Graph chunk
// staged in LDS with BN+ReLU applied once. Partials -> part (1024 x 8192).
// ---------------------------------------------------------------------------
__global__ __launch_bounds__(256) void k_headgemm_v3(
    const float* __restrict__ pre2, const float* __restrict__ scsh,
    const float* __restrict__ Wm1, float* __restrict__ part) {
  __shared__ float graphS[64][128];   // 32 KB
  const int t = threadIdx.x;
  const int bid = blockIdx.x;
  const int k0 = bid * 128;
  const int cbase = k0 & 255;

  #pragma unroll
  for (int l = 0; l < 8; ++l) {
    const int f = t + 256 * l;
    const int row = f >> 5, c4 = (f & 31) * 4;
    const float4 p = *(const float4*)(pre2 + (size_t)row * FEAT_ + k0 + c4);
    const float4 sc = *(const float4*)(scsh + cbase + c4);
    const float4 sh = *(const float4*)(scsh + 256 + cbase + c4);
    graphS[row][c4 + 0] = fmaxf(p.x * sc.x + sh.x, 0.0f);
    graphS[row][c4 + 1] = fmaxf(p.y * sc.y + sh.y, 0.0f);
    graphS[row][c4 + 2] = fmaxf(p.z * sc.z + sh.z, 0.0f);
    graphS[row][c4 + 3] = fmaxf(p.w * sc.w + sh.w, 0.0f);
  }
  __syncthreads();

  const int hg = t & 31;
  const int bg = t >> 5;
  float acc[8][4];
  #pragma unroll
  for (int i = 0; i < 8; ++i)
    #pragma unroll
    for (int j = 0; j < 4; ++j) acc[i][j] = 0.f;

  #pragma unroll 2
  for (int kk = 0; kk < 128; kk += 4) {
    const int k = k0 + kk;
    const float4 w0 = *(const float4*)(Wm1 + (size_t)(k + 0) * 128 + hg * 4);
    const float4 w1 = *(const float4*)(Wm1 + (size_t)(k + 1) * 128 + hg * 4);
    const float4 w2 = *(const float4*)(Wm1 + (size_t)(k + 2) * 128 + hg * 4);
    const float4 w3 = *(const float4*)(Wm1 + (size_t)(k + 3) * 128 + hg * 4);
    #pragma unroll
    for (int i = 0; i < 8; ++i) {
      const float4 a = *(const float4*)&graphS[bg * 8 + i][kk];
      acc[i][0] += a.x * w0.x; acc[i][1] += a.x * w0.y;
      acc[i][2] += a.x * w0.z; acc[i][3] += a.x * w0.w;
      acc[i][0] += a.y * w1.x; acc[i][1] += a.y * w1.y;
      acc[i][2] += a.y * w1.z; acc[i][3] += a.y * w1.w;
      acc[i][0] += a.z * w2.x; acc[i][1] += a.z * w2.y;
      acc[i][2] += a.z * w2.z; acc[i][3] += a.z * w2.w;
      acc[i][0] += a.w * w3.x; acc[i][1] += a.w * w3.y;
      acc[i][2] += a.w * w3.z; acc[i][3] += a.w * w3.w;
    }
  }

  float* pb = part + (size_t)bid * 8192;
  #pragma unroll
  for (int i = 0; i < 8; ++i)
    *(float4*)(pb + (bg * 8 + i) * 128 + hg * 4) =
        make_float4(acc[i][0], acc[i][1], acc[i][2], acc[i][3]);
}

// ---------------------------------------------------------------------------
// head reduce stage A: part2[jg][o] = sum of 128 consecutive partials.
// ---------------------------------------------------------------------------
__global__ __launch_bounds__(256) void k_headredA(
    const float* __restrict__ part, float* __restrict__ part2) {
  const int o = blockIdx.x * 256 + threadIdx.x;
  const int jg = blockIdx.y;
  const float* base = part + (size_t)jg * 128 * 8192;
  float s = 0.f;
  for (int j = 0; j < 128; ++j) s += base[(size_t)j * 8192 + o];
  part2[(size_t)jg * 8192 + o] = s;
}

// head reduce stage B: z1[o] = sum_{jg<8} part2[jg][o]
__global__ __launch_bounds__(256) void k_headredB(
    const float* __restrict__ part2, float* __restrict__ z1) {
  const int o = blockIdx.x * 256 + threadIdx.x;
  float s = 0.f;
  #pragma unroll
  for (int jg = 0; jg < 8; ++jg) s += part2[(size_t)jg * 8192 + o];
  z1[o] = s;
}

// ---------------------------------------------------------------------------
// head BN over batch (J features) + ReLU
// ---------------------------------------------------------------------------
template <int J>
__global__ __launch_bounds__(64) void k_headbn(
    const float* __restrict__ z, const float* __restrict__ g,
    const float* __restrict__ be, float* __restrict__ zr) {
  __shared__ float rs[64], rs2[64];
  const int j = blockIdx.x, b = threadIdx.x;
  const float v = z[b * J + j];
  rs[b] = v; rs2[b] = v * v; __syncthreads();
  for (int s = 32; s; s >>= 1) {
    if (b < s) { rs[b] += rs[b + s]; rs2[b] += rs2[b + s]; }
    __syncthreads();
  }
  const float m = rs[0] * (1.0f / 64.0f);
  const float var = rs2[0] * (1.0f / 64.0f) - m * m;
  const float sc = g[j] * rsqrtf(var + 1e-5f);
  const float sh = be[j] - m * sc;
  zr[b * J + j] = fmaxf(v * sc + sh, 0.0f);
}

__global__ __launch_bounds__(64) void k_headmm2(
    const float* __restrict__ zr1, const float* __restrict__ Wm2,
    float* __restrict__ z2) {
  const int b = blockIdx.x, j = threadIdx.x;
  float acc = 0.f;
  for (int k = 0; k < 128; ++k) acc += zr1[b * 128 + k] * Wm2[k * 64 + j];
  z2[b * 64 + j] = acc;
}

__global__ __launch_bounds__(128) void k_headout(
    const float* __restrict__ zr2, const float* __restrict__ Wm3,
    const float* __restrict__ bm3, float* __restrict__ out) {
  const int t = threadIdx.x;
  const int b = t >> 1, c = t & 1;
  float s = bm3[c];
  for (int k = 0; k < 64; ++k) s += zr2[b * 64 + k] * Wm3[k * 2 + c];
  out[t] = s;
}

// ---------------------------------------------------------------------------
extern "C" void kernel_launch(void* const* d_in, const int* in_sizes, int n_in,
                              void* d_out, int out_size, void* d_ws, size_t ws_size,
                              hipStream_t stream) {
  (void)in_sizes; (void)n_in; (void)out_size; (void)ws_size;
  const float* x    = (const float*)d_in[0];
  const float* mask = (const float*)d_in[1];
  const float* W1   = (const float*)d_in[2];
  const float* b1   = (const float*)d_in[3];
  const float* g1   = (const float*)d_in[4];
  const float* be1  = (const float*)d_in[5];
  const float* W2   = (const float*)d_in[6];
  const float* b2   = (const float*)d_in[7];
  const float* g2   = (const float*)d_in[8];
  const float* be2  = (const float*)d_in[9];
  const float* Wm1  = (const float*)d_in[10];
  // d_in[11] = bm1 (zeros; cancels under BN)
  const float* gm1  = (const float*)d_in[12];
  const float* bem1 = (const float*)d_in[13];
  const float* Wm2  = (const float*)d_in[14];
  // d_in[15] = bm2 (zeros; cancels under BN)
  const float* gm2  = (const float*)d_in[16];
  const float* bem2 = (const float*)d_in[17];
  const float* Wm3  = (const float*)d_in[18];
  const float* bm3  = (const float*)d_in[19];

  // workspace (floats), same extent as verified previously (117.67 MB)
  float* ws   = (float*)d_ws;
  float* T1   = ws;                 // 8,388,608 : xn -> bn partials
  float* An   = T1 + 8388608;       // 4,194,304 : An -> head part2
  float* T2   = An + 4194304;       // 8,388,608 : XW1 -> XW2 -> head partials
  float* T3   = T2 + 8388608;       // 8,388,608 : pre1 -> pre2
  float* z1   = T3 + 8388608;       // 8,192
  float* dinv = z1 + 8192;          // 32,768 : scsh1 at +0, scsh2 at +512
  float* st1  = dinv + 32768;       // 512 (unused, kept for layout)
  float* st2  = st1 + 512;          // 512 (unused)
  float* zr1  = st2 + 512;          // 8,192
  float* z2   = zr1 + 8192;         // 4,096
  float* zr2  = z2 + 4096;          // 4,096

  float* scsh1 = dinv;
  float* scsh2 = dinv + 512;

  // edges / An (fused: sim + deg + normalize)
  k_xn<<<8192, 256, 0, stream>>>(x, T1);
  k_simfused<<<256, 256, 0, stream>>>(T1, mask, An);

  // layer 1: pre1 = An @ (x@W1+b1); stats fused into bmm
  k_gemm_t<<<dim3(512, 2), 256, 0, stream>>>(x, W1, b1, T2);
  k_bmmst<<<dim3(256, 4), 256, 0, stream>>>(An, T2, T3, T1);   // T1: xn dead
  k_bnscsh<<<256, 256, 0, stream>>>(T1, g1, be1, scsh1);

  // layer 2: pre2 = An @ (relu(bn(pre1))@W2+b2); bn fused into A-staging
  k_gemmbn_t<<<dim3(512, 2), 256, 0, stream>>>(T3, scsh1, W2, b2, T2);
  k_bmmst<<<dim3(256, 4), 256, 0, stream>>>(An, T2, T3, T1);
  k_bnscsh<<<256, 256, 0, stream>>>(T1, g2, be2, scsh2);

  // head: z1 = relu(bn(pre2)) @ Wm1, LDS-staged split-K + 2-stage reduce
  k_headgemm_v3<<<1024, 256, 0, stream>>>(T3, scsh2, Wm1, T2);
  k_headredA<<<dim3(32, 8), 256, 0, stream>>>(T2, An);
  k_headredB<<<32, 256, 0, stream>>>(An, z1);
  k_headbn<128><<<128, 64, 0, stream>>>(z1, gm1, bem1, zr1);
  k_headmm2<<<64, 64, 0, stream>>>(zr1, Wm2, z2);
  k_headbn<64><<<64, 64, 0, stream>>>(z2, gm2, bem2, zr2);
  k_headout<<<1, 128, 0, stream>>>(zr2, Wm3, bm3, (float*)d_out);
}

// Round 10
// 426.116 us; speedup vs baseline: 1.0869x; 1.0386x over previous
//
#include <hip/hip_runtime.h>
#include <cstdint>
#include <cstddef>

// Shapes (fixed): B=64, N=4, P=128, d=h=256, totP=512, feat=131072
#define P_    128
#define H_    256
#define FEAT_ 131072

// ---------------------------------------------------------------------------
// Fused sim + deg + sym-normalize, reading RAW x (normalization factorized:
// dot(xn_p,xn_q) = G[pq]*inv_p*inv_q, ||x_p||^2 = G[pp]). One block per blk.
// ---------------------------------------------------------------------------
__global__ __launch_bounds__(256) void k_simfused(
    const float* __restrict__ x, const float* __restrict__ mask,
    float* __restrict__ An) {
  __shared__ float Xs[16][128];      // [k][row], chunk of K
  __shared__ float red[128][17];     // row partial sums
  __shared__ float diag_s[128];
  __shared__ float inv_s[128];
  __shared__ float dinv_s[128];
  const int blk = blockIdx.x;
  const int t = threadIdx.x;
  const int tp = t >> 4, tq = t & 15;   // rows tp*8..+7, cols tq*8..+7
  const float* Xb = x + (size_t)blk * (128 * 256);

  float v[8][8];
  #pragma unroll
  for (int i = 0; i < 8; ++i)
    #pragma unroll
    for (int j = 0; j < 8; ++j) v[i][j] = 0.f;

  for (int kc = 0; kc < 16; ++kc) {
    __syncthreads();
    #pragma unroll
    for (int l = 0; l < 2; ++l) {
      const int f = t + 256 * l;
      const int row = f >> 2, k4 = (f & 3) * 4;
      const float4 x4 = *(const float4*)(Xb + (size_t)row * 256 + kc * 16 + k4);
      Xs[k4 + 0][row] = x4.x;
      Xs[k4 + 1][row] = x4.y;
      Xs[k4 + 2][row] = x4.z;
      Xs[k4 + 3][row] = x4.w;
    }
    __syncthreads();
    #pragma unroll
    for (int k = 0; k < 16; ++k) {
      const float4 a0 = *(const float4*)&Xs[k][tp * 8];
      const float4 a1 = *(const float4*)&Xs[k][tp * 8 + 4];
      const float4 b0 = *(const float4*)&Xs[k][tq * 8];
      const float4 b1 = *(const float4*)&Xs[k][tq * 8 + 4];
      const float a[8] = {a0.x, a0.y, a0.z, a0.w, a1.x, a1.y, a1.z, a1.w};
      const float b[8] = {b0.x, b0.y, b0.z, b0.w, b1.x, b1.y, b1.z, b1.w};
      #pragma unroll
      for (int i = 0; i < 8; ++i)
        #pragma unroll
        for (int j = 0; j < 8; ++j) v[i][j] += a[i] * b[j];
    }
  }

  // diagonal -> row norms -> inverse norms (matches x / max(||x||, 1e-12))
  if (tp == tq) {
    #pragma unroll
    for (int i = 0; i < 8; ++i) diag_s[tp * 8 + i] = v[i][i];
  }
  __syncthreads();
  if (t < 128) inv_s[t] = 1.0f / fmaxf(sqrtf(diag_s[t]), 1e-12f);
  __syncthreads();

  float ivq[8];
  #pragma unroll
  for (int j = 0; j < 8; ++j) ivq[j] = inv_s[tq * 8 + j];

  #pragma unroll
  for (int i = 0; i < 8; ++i) {
    const int r = tp * 8 + i;
    const float ivp = inv_s[r];
    const float4 m0 = *(const float4*)(mask + r * 128 + tq * 8);
    const float4 m1 = *(const float4*)(mask + r * 128 + tq * 8 + 4);
    const float mm[8] = {m0.x, m0.y, m0.z, m0.w, m1.x, m1.y, m1.z, m1.w};
    float s = 0.f;
    #pragma unroll
    for (int j = 0; j < 8; ++j) {
      const int c = tq * 8 + j;
      const float vv = (r == c) ? 0.0f
                                : (v[i][j] * ivp * ivq[j] + 1.0f) * 0.5f * mm[j];
      v[i][j] = vv;
      s += vv;
    }
    red[r][tq] = s;
  }
  __syncthreads();
  if (t < 128) {
    float sm = 0.f;
    #pragma unroll
    for (int u = 0; u < 16; ++u) sm += red[t][u];
    const float deg = 1.0f + sm;
    dinv_s[t] = (deg > 0.0f) ? rsqrtf(fmaxf(deg, 1e-12f)) : 0.0f;
  }
  __syncthreads();

  float dq[8];
  #pragma unroll
  for (int j = 0; j < 8; ++j) dq[j] = dinv_s[tq * 8 + j];
  float* Ab = An + (size_t)blk * 16384;
  #pragma unroll
  for (int i = 0; i < 8; ++i) {
    const int r = tp * 8 + i;
    const float dp = dinv_s[r];
    float o[8];
    #pragma unroll
    for (int j = 0; j < 8; ++j) {
      const int c = tq * 8 + j;
      o[j] = (r == c) ? dp * dq[j] : v[i][j] * dp * dq[j];
    }
    *(float4*)(Ab + (size_t)r * 128 + tq * 8)     = make_float4(o[0], o[1], o[2], o[3]);
    *(float4*)(Ab + (size_t)r * 128 + tq * 8 + 4) = make_float4(o[4], o[5], o[6], o[7]);
  }
}

// ---------------------------------------------------------------------------
// Tiled GEMM (layer 1): out[32768][256] = A @ W + bias. 64x128 tile,
// grid (512,2), 256 thr, 4x8/thread. (R7-verified form, VGPR 40.)
// ---------------------------------------------------------------------------
__global__ __launch_bounds__(256) void k_gemm_t(
    const float* __restrict__ A, const float* __restrict__ W,
    const float* __restrict__ bias, float* __restrict__ out) {
  __shared__ float As[16][64];    // [k][row]
  __shared__ float Ws[16][128];   // [k][col]
  const int rb = blockIdx.x, cb = blockIdx.y;
  const int t = threadIdx.x, tp = t >> 4, tq = t & 15;
  const int m0 = rb * 64, c0 = cb * 128;

  float acc[4][8];
  #pragma unroll
  for (int j = 0; j < 8; ++j) {
    const int col = c0 + ((j < 4) ? (tq * 4 + j) : (64 + tq * 4 + j - 4));
    const float bj = bias[col];
    #pragma unroll
    for (int i = 0; i < 4; ++i) acc[i][j] = bj;
  }

  for (int kc = 0; kc < 16; ++kc) {
    __syncthreads();
    {   // stage A tile: 64 rows x 16 k
      const int row = t >> 2, k4 = (t & 3) * 4;
      const float4 a4 = *(const float4*)(A + (size_t)(m0 + row) * 256 + kc * 16 + k4);
      As[k4 + 0][row] = a4.x;
      As[k4 + 1][row] = a4.y;
      As[k4 + 2][row] = a4.z;
      As[k4 + 3][row] = a4.w;
    }
    #pragma unroll
    for (int l = 0; l < 2; ++l) {   // stage W tile: 16 k x 128 cols
      const int f = t + 256 * l;
      const int k = f >> 5, c4 = (f & 31) * 4;
      *(float4*)&Ws[k][c4] =
          *(const float4*)(W + (size_t)(kc * 16 + k) * 256 + c0 + c4);
    }
    __syncthreads();
    #pragma unroll
    for (int k = 0; k < 16; ++k) {
      const float4 av = *(const float4*)&As[k][tp * 4];
      const float4 w0 = *(const float4*)&Ws[k][tq * 4];
      const float4 w1 = *(const float4*)&Ws[k][64 + tq * 4];
      const float a[4] = {av.x, av.y, av.z, av.w};
      const float w[8] = {w0.x, w0.y, w0.z, w0.w, w1.x, w1.y, w1.z, w1.w};
      #pragma unroll
      for (int i = 0; i < 4; ++i)
        #pragma unroll
        for (int j = 0; j < 8; ++j) acc[i][j] += a[i] * w[j];
    }
  }

  #pragma unroll
  for (int i = 0; i < 4; ++i) {
    float* orow = out + (size_t)(m0 + tp * 4 + i) * 256 + c0;
    *(float4*)(orow + tq * 4)      = make_float4(acc[i][0], acc[i][1], acc[i][2], acc[i][3]);
    *(float4*)(orow + 64 + tq * 4) = make_float4(acc[i][4], acc[i][5], acc[i][6], acc[i][7]);
  }
}

// ---------------------------------------------------------------------------
// Tiled GEMM (layer 2), same structure, fused BN+ReLU on A staging.
// scsh: [0..255]=sc, [256..511]=sh; channel = k index. (R7-verified form.)
// ---------------------------------------------------------------------------
__global__ __launch_bounds__(256) void k_gemmbn_t(
    const float* __restrict__ A, const float* __restrict__ scsh,
    const float* __restrict__ W, const float* __restrict__ bias,
    float* __restrict__ out) {
  __shared__ float As[16][64];
  __shared__ float Ws[16][128];
  const int rb = blockIdx.x, cb = blockIdx.y;
  const int t = threadIdx.x, tp = t >> 4, tq = t & 15;
  const int m0 = rb * 64, c0 = cb * 128;

  float acc[4][8];
  #pragma unroll
  for (int j = 0; j < 8; ++j) {
    const int col = c0 + ((j < 4) ? (tq * 4 + j) : (64 + tq * 4 + j - 4));
    const float bj = bias[col];
    #pragma unroll
    for (int i = 0; i < 4; ++i) acc[i][j] = bj;
  }

  for (int kc = 0; kc < 16; ++kc) {
    __syncthreads();
    {   // stage A tile with BN+ReLU (channel = k index)
      const int row = t >> 2, k4 = (t & 3) * 4;
      const int col = kc * 16 + k4;
      const float4 a4 = *(const float4*)(A + (size_t)(m0 + row) * 256 + col);
      const float4 sc = *(const float4*)(scsh + col);
      const float4 sh = *(const float4*)(scsh + 256 + col);
      As[k4 + 0][row] = fmaxf(a4.x * sc.x + sh.x, 0.0f);
      As[k4 + 1][row] = fmaxf(a4.y * sc.y + sh.y, 0.0f);
      As[k4 + 2][row] = fmaxf(a4.z * sc.z + sh.z, 0.0f);
      As[k4 + 3][row] = fmaxf(a4.w * sc.w + sh.w, 0.0f);
    }
    #pragma unroll
    for (int l = 0; l < 2; ++l) {
      const int f = t + 256 * l;
      const int k = f >> 5, c4 = (f & 31) * 4;
      *(float4*)&Ws[k][c4] =
          *(const float4*)(W + (size_t)(kc * 16 + k) * 256 + c0 + c4);
    }
    __syncthreads();
    #pragma unroll
    for (int k = 0; k < 16; ++k) {
      const float4 av = *(const float4*)&As[k][tp * 4];
      const float4 w0 = *(const float4*)&Ws[k][tq * 4];
      const float4 w1 = *(const float4*)&Ws[k][64 + tq * 4];
      const float a[4] = {av.x, av.y, av.z, av.w};
      const float w[8] = {w0.x, w0.y, w0.z, w0.w, w1.x, w1.y, w1.z, w1.w};
      #pragma unroll
      for (int i = 0; i < 4; ++i)
        #pragma unroll
        for (int j = 0; j < 8; ++j) acc[i][j] += a[i] * w[j];
    }
  }

  #pragma unroll
  for (int i = 0; i < 4; ++i) {
    float* orow = out + (size_t)(m0 + tp * 4 + i) * 256 + c0;
    *(float4*)(orow + tq * 4)      = make_float4(acc[i][0], acc[i][1], acc[i][2], acc[i][3]);
    *(float4*)(orow + 64 + tq * 4) = make_float4(acc[i][4], acc[i][5], acc[i][6], acc[i][7]);
  }
}

// ---------------------------------------------------------------------------
// Tiled bmm + fused BN-stat partials, 64x128 tile, grid (256,4).
// y = rh*2+cb. part[(blk*4+y)*256 + {c | 128+c}]. (R7-verified form.)
// ---------------------------------------------------------------------------
__global__ __launch_bounds__(256) void k_bmmst(
    const float* __restrict__ An, const float* __restrict__ XW,
    float* __restrict__ out, float* __restrict__ part) {
  __shared__ float As[16][64];    // [q][p]
  __shared__ float Ws[16][128];   // [q][c]
  __shared__ float rs[16][128];
  __shared__ float rq[16][128];
  const int blk = blockIdx.x;
  const int y = blockIdx.y;            // 0..3
  const int rh = y >> 1, cb = y & 1;
  const int t = threadIdx.x, tp = t >> 4, tq = t & 15;
  const float* Ab = An + (size_t)blk * 16384 + (size_t)rh * 64 * 128;
  const float* Xb = XW + (size_t)blk * (128 * 256);

  float acc[4][8];
  #pragma unroll
  for (int i = 0; i < 4; ++i)
    #pragma unroll
    for (int j = 0; j < 8; ++j) acc[i][j] = 0.f;

  for (int kc = 0; kc < 8; ++kc) {     // K=128, ascending q
    __syncthreads();
    {   // stage An tile: 64 p x 16 q
      const int row = t >> 2, k4 = (t & 3) * 4;
      const float4 a4 = *(const float4*)(Ab + (size_t)row * 128 + kc * 16 + k4);
      As[k4 + 0][row] = a4.x;
      As[k4 + 1][row] = a4.y;
      As[k4 + 2][row] = a4.z;
      As[k4 + 3][row] = a4.w;
    }
    #pragma unroll
    for (int l = 0; l < 2; ++l) {      // stage XW tile: 16 q x 128 c
      const int f = t + 256 * l;
      const int k = f >> 5, c4 = (f & 31) * 4;
      *(float4*)&Ws[k][c4] =
          *(const float4*)(Xb + (size_t)(kc * 16 + k) * 256 + cb * 128 + c4);
    }
    __syncthreads();
    #pragma unroll
    for (int k = 0; k < 16; ++k) {
      const float4 av = *(const float4*)&As[k][tp * 4];
      const float4 w0 = *(const float4*)&Ws[k][tq * 4];
      const float4 w1 = *(const float4*)&Ws[k][64 + tq * 4];
      const float a[4] = {av.x, av.y, av.z, av.w};
      const float w[8] = {w0.x, w0.y, w0.z, w0.w, w1.x, w1.y, w1.z, w1.w};
      #pragma unroll
      for (int i = 0; i < 4; ++i)
        #pragma unroll
        for (int j = 0; j < 8; ++j) acc[i][j] += a[i] * w[j];
    }
  }

  // stats: per-thread col partial over 4 rows -> LDS -> 128-thread final
  #pragma unroll
  for (int j = 0; j < 8; ++j) {
    float cs = 0.f, cq = 0.f;
    #pragma unroll
    for (int i = 0; i < 4; ++i) { cs += acc[i][j]; cq += acc[i][j] * acc[i][j]; }
    const int col = (j < 4) ? (tq * 4 + j) : (64 + tq * 4 + j - 4);
    rs[tp][col] = cs;
    rq[tp][col] = cq;
  }
  __syncthreads();
  if (t < 128) {
    float s = 0.f, q = 0.f;
    #pragma unroll
    for (int u = 0; u < 16; ++u) { s += rs[u][t]; q += rq[u][t]; }
    const int base = (blk * 4 + y) * 256;
    part[base + t]       = s;
    part[base + 128 + t] = q;
  }

  #pragma unroll
  for (int i = 0; i < 4; ++i) {
    float* orow = out + (size_t)(blk * 128 + rh * 64 + tp * 4 + i) * 256 + cb * 128;
    *(float4*)(orow + tq * 4)      = make_float4(acc[i][0], acc[i][1], acc[i][2], acc[i][3]);
    *(float4*)(orow + 64 + tq * 4) = make_float4(acc[i][4], acc[i][5], acc[i][6], acc[i][7]);
  }
}

// ---------------------------------------------------------------------------
// bn final + scsh: block per channel (256 blocks x 256 thr). Deterministic.
// ---------------------------------------------------------------------------
__global__ __launch_bounds__(256) void k_bnscsh(
    const float* __restrict__ part, const float* __restrict__ g,
    const float* __restrict__ be, float* __restrict__ scsh) {
  __shared__ float ss[256], qq[256];
  const int c = blockIdx.x;
  const int cb = c >> 7, lc = c & 127;
  const int u = threadIdx.x;           // = blk
  const float* p0 = part + (size_t)(u * 4 + cb) * 256;        // rh=0
  const float* p1 = part + (size_t)(u * 4 + 2 + cb) * 256;    // rh=1
  ss[u] = p0[lc] + p1[lc];
  qq[u] = p0[128 + lc] + p1[128 + lc];
  __syncthreads();
  for (int st = 128; st; st >>= 1) {
    if (u < st) { ss[u] += ss[u + st]; qq[u] += qq[u + st]; }
    __syncthreads();
  }
  if (u == 0) {
    const float m = ss[0] * (1.0f / 32768.0f);
    const float var = qq[0] * (1.0f / 32768.0f) - m * m;
    const float sc = g[c] * rsqrtf(var + 1e-5f);
    scsh[c] = sc;
    scsh[256 + c] = be[c] - m * sc;
  }
}

// ---------------------------------------------------------------------------
// head split-K GEMM v3: 1024 blocks (K-chunk 128) x 256 thr. Graph chunk
// staged in LDS with BN+ReLU applied once. Partials -> part (1024 x 8192).
// ---------------------------------------------------------------------------
__global__ __launch_bounds__(256) void k_headgemm_v3(
    const float* __restrict__ pre2, const float* __restrict__ scsh,
    const float* __restrict__ Wm1, float* __restrict__ part) {
  __shared__ float graphS[64][128];   // 32 KB
  const int t = threadIdx.x;
  const int bid = blockIdx.x;
  const int k0 = bid * 128;
  const int cbase = k0 & 255;

  #pragma unroll
  for (int l = 0; l < 8; ++l) {
    const int f = t + 256 * l;
    const int row = f >> 5, c4 = (f & 31) * 4;
    const float4 p = *(const float4*)(pre2 + (size_t)row * FEAT_ + k0 + c4);
    const float4 sc = *(const float4*)(scsh + cbase + c4);
    const float4 sh = *(const float4*)(scsh + 256 + cbase + c4);
    graphS[row][c4 + 0] = fmaxf(p.x * sc.x + sh.x, 0.0f);
    graphS[row][c4 + 1] = fmaxf(p.y * sc.y + sh.y, 0.0f);
    graphS[row][c4 + 2] = fmaxf(p.z * sc.z + sh.z, 0.0f);
    graphS[row][c4 + 3] = fmaxf(p.w * sc.w + sh.w, 0.0f);
  }
  __syncthreads();

  const int hg = t & 31;
  const int bg = t >> 5;
  float acc[8][4];
  #pragma unroll
  for (int i = 0; i < 8; ++i)
    #pragma unroll
    for (int j = 0; j < 4; ++j) acc[i][j] = 0.f;

  #pragma unroll 2
  for (int kk = 0; kk < 128; kk += 4) {
    const int k = k0 + kk;
    const float4 w0 = *(const float4*)(Wm1 + (size_t)(k + 0) * 128 + hg * 4);
    const float4 w1 = *(const float4*)(Wm1 + (size_t)(k + 1) * 128 + hg * 4);
    const float4 w2 = *(const float4*)(Wm1 + (size_t)(k + 2) * 128 + hg * 4);
    const float4 w3 = *(const float4*)(Wm1 + (size_t)(k + 3) * 128 + hg * 4);
    #pragma unroll
    for (int i = 0; i < 8; ++i) {
      const float4 a = *(const float4*)&graphS[bg * 8 + i][kk];
      acc[i][0] += a.x * w0.x; acc[i][1] += a.x * w0.y;
      acc[i][2] += a.x * w0.z; acc[i][3] += a.x * w0.w;
      acc[i][0] += a.y * w1.x; acc[i][1] += a.y * w1.y;
      acc[i][2] += a.y * w1.z; acc[i][3] += a.y * w1.w;
      acc[i][0] += a.z * w2.x; acc[i][1] += a.z * w2.y;
      acc[i][2] += a.z * w2.z; acc[i][3] += a.z * w2.w;
      acc[i][0] += a.w * w3.x; acc[i][1] += a.w * w3.y;
      acc[i][2] += a.w * w3.z; acc[i][3] += a.w * w3.w;
    }
  }

  float* pb = part + (size_t)bid * 8192;
  #pragma unroll
  for (int i = 0; i < 8; ++i)
    *(float4*)(pb + (bg * 8 + i) * 128 + hg * 4) =
        make_float4(acc[i][0], acc[i][1], acc[i][2], acc[i][3]);
}

// ---------------------------------------------------------------------------
// head reduce stage A: part2[jg][o] = sum of 128 consecutive partials.
// ---------------------------------------------------------------------------
__global__ __launch_bounds__(256) void k_headredA(
    const float* __restrict__ part, float* __restrict__ part2) {
  const int o = blockIdx.x * 256 + threadIdx.x;
  const int jg = blockIdx.y;
  const float* base = part + (size_t)jg * 128 * 8192;
  float s = 0.f;
  for (int j = 0; j < 128; ++j) s += base[(size_t)j * 8192 + o];
  part2[(size_t)jg * 8192 + o] = s;
}

// ---------------------------------------------------------------------------
// Fused head tail: z1 reduce -> BN1+ReLU -> mm2 -> BN2+ReLU -> out.
// ONE block, 256 threads, everything in LDS (~81 KB). Replaces 5 dispatches.
// mm2 keeps the original ascending-k single-FMA-per-k order exactly.
// ---------------------------------------------------------------------------
__global__ __launch_bounds__(256) void k_headtail(
    const float* __restrict__ part2,
    const float* __restrict__ gm1, const float* __restrict__ bem1,
    const float* __restrict__ Wm2,
    const float* __restrict__ gm2, const float* __restrict__ bem2,
    const float* __restrict__ Wm3, const float* __restrict__ bm3,
    float* __restrict__ out) {
  __shared__ float zs[8192];     // z1 / zr1 (64x128)
  __shared__ float wm2s[8192];   // Wm2 (128x64)
  __shared__ float zb2[4096];    // z2 / zr2 (64x64)
  __shared__ float sc1[128], sh1[128], sc2[64], sh2[64];
  const int t = threadIdx.x;

  // z1[o] = sum_{jg<8} part2[jg][o]  (same order as old k_headredB)
  for (int o = t; o < 8192; o += 256) {
    float s = 0.f;
    #pragma unroll
    for (int jg = 0; jg < 8; ++jg) s += part2[(size_t)jg * 8192 + o];
    zs[o] = s;
  }
  for (int o = t; o < 8192; o += 256) wm2s[o] = Wm2[o];
  __syncthreads();

  // BN1 stats over batch (64) per feature
  if (t < 128) {
    float s = 0.f, q = 0.f;
    for (int b = 0; b < 64; ++b) { const float v = zs[b * 128 + t]; s += v; q += v * v; }
    const float m = s * (1.0f / 64.0f);
    const float var = q * (1.0f / 64.0f) - m * m;
    const float sc = gm1[t] * rsqrtf(var + 1e-5f);
    sc1[t] = sc; sh1[t] = bem1[t] - m * sc;
  }
  __syncthreads();
  for (int o = t; o < 8192; o += 256)
    zs[o] = fmaxf(zs[o] * sc1[o & 127] + sh1[o & 127], 0.0f);
  __syncthreads();

  // mm2: z2[b][j] = sum_k zr1[b][k]*Wm2[k][j]; 4x4 register tile per thread
  {
    const int bq = t >> 4, jq = t & 15;    // b-quad, j-quad
    float acc[4][4];
    #pragma unroll
    for (int bi = 0; bi < 4; ++bi)
      #pragma unroll
      for (int ji = 0; ji < 4; ++ji) acc[bi][ji] = 0.f;
    for (int k = 0; k < 128; ++k) {        // ascending k, one FMA per k
      const float4 w4 = *(const float4*)&wm2s[k * 64 + jq * 4];
      const float wv[4] = {w4.x, w4.y, w4.z, w4.w};
      #pragma unroll
      for (int bi = 0; bi < 4; ++bi) {
        const float zv = zs[(bq * 4 + bi) * 128 + k];
        #pragma unroll
        for (int ji = 0; ji < 4; ++ji) acc[bi][ji] += zv * wv[ji];
      }
    }
    #pragma unroll
    for (int bi = 0; bi < 4; ++bi)
      #pragma unroll
      for (int ji = 0; ji < 4; ++ji)
        zb2[(bq * 4 + bi) * 64 + jq * 4 + ji] = acc[bi][ji];
  }
  __syncthreads();

  // BN2 stats over batch (64) per feature
  if (t < 64) {
    float s = 0.f, q = 0.f;
    for (int b = 0; b < 64; ++b) { const float v = zb2[b * 64 + t]; s += v; q += v * v; }
    const float m = s * (1.0f / 64.0f);
    const float var = q * (1.0f / 64.0f) - m * m;
    const float sc = gm2[t] * rsqrtf(var + 1e-5f);
    sc2[t] = sc; sh2[t] = bem2[t] - m * sc;
  }
  __syncthreads();
  for (int idx = t; idx < 4096; idx += 256)
    zb2[idx] = fmaxf(zb2[idx] * sc2[idx & 63] + sh2[idx & 63], 0.0f);
  __syncthreads();

  // out[b][c] = bm3[c] + sum_k zr2[b][k]*Wm3[k][c]
  if (t < 128) {
    const int b = t >> 1, c = t & 1;
    float s = bm3[c];
    for (int k = 0; k < 64; ++k) s += zb2[b * 64 + k] * Wm3[k * 2 + c];
    out[t] = s;
  }
}

// ---------------------------------------------------------------------------
extern "C" void kernel_launch(void* const* d_in, const int* in_sizes, int n_in,
                              void* d_out, int out_size, void* d_ws, size_t ws_size,
                              hipStream_t stream) {
  (void)in_sizes; (void)n_in; (void)out_size; (void)ws_size;
  const float* x    = (const float*)d_in[0];
  const float* mask = (const float*)d_in[1];
  const float* W1   = (const float*)d_in[2];
  const float* b1   = (const float*)d_in[3];
  const float* g1   = (const float*)d_in[4];
  const float* be1  = (const float*)d_in[5];
  const float* W2   = (const float*)d_in[6];
  const float* b2   = (const float*)d_in[7];
  const float* g2   = (const float*)d_in[8];
  const float* be2  = (const float*)d_in[9];
  const float* Wm1  = (const float*)d_in[10];
  // d_in[11] = bm1 (zeros; cancels under BN)
  const float* gm1  = (const float*)d_in[12];
  const float* bem1 = (const float*)d_in[13];
  const float* Wm2  = (const float*)d_in[14];
  // d_in[15] = bm2 (zeros; cancels under BN)
  const float* gm2  = (const float*)d_in[16];
  const float* bem2 = (const float*)d_in[17];
  const float* Wm3  = (const float*)d_in[18];
  const float* bm3  = (const float*)d_in[19];

  // workspace (floats), same extent as verified previously (117.67 MB)
  float* ws   = (float*)d_ws;
  float* T1   = ws;                 // 8,388,608 : bn partials
  float* An   = T1 + 8388608;       // 4,194,304 : An -> head part2
  float* T2   = An + 4194304;       // 8,388,608 : XW1 -> XW2 -> head partials
  float* T3   = T2 + 8388608;       // 8,388,608 : pre1 -> pre2
  float* z1   = T3 + 8388608;       // 8,192 (unused now)
  float* dinv = z1 + 8192;          // 32,768 : scsh1 at +0, scsh2 at +512
  (void)z1;

  float* scsh1 = dinv;
  float* scsh2 = dinv + 512;

  // edges / An (fused: Gram + norm-factorized sim + deg + normalize)
  k_simfused<<<256, 256, 0, stream>>>(x, mask, An);

  // layer 1: pre1 = An @ (x@W1+b1); stats fused into bmm
  k_gemm_t<<<dim3(512, 2), 256, 0, stream>>>(x, W1, b1, T2);
  k_bmmst<<<dim3(256, 4), 256, 0, stream>>>(An, T2, T3, T1);
  k_bnscsh<<<256, 256, 0, stream>>>(T1, g1, be1, scsh1);

  // layer 2: pre2 = An @ (relu(bn(pre1))@W2+b2); bn fused into A-staging
  k_gemmbn_t<<<dim3(512, 2), 256, 0, stream>>>(T3, scsh1, W2, b2, T2);
  k_bmmst<<<dim3(256, 4), 256, 0, stream>>>(An, T2, T3, T1);
  k_bnscsh<<<256, 256, 0, stream>>>(T1, g2, be2, scsh2);

  // head: z1 = relu(bn(pre2)) @ Wm1, split-K + reduce + fused tail
  k_headgemm_v3<<<1024, 256, 0, stream>>>(T3, scsh2, Wm1, T2);
  k_headredA<<<dim3(32, 8), 256, 0, stream>>>(T2, An);
  k_headtail<<<1, 256, 0, stream>>>(An, gm1, bem1, Wm2, gm2, bem2,
                                    Wm3, bm3, (float*)d_out);
}

// Round 11
// 412.467 us; speedup vs baseline: 1.1229x; 1.0331x over previous
//
#include <hip/hip_runtime.h>
#include <cstdint>
#include <cstddef>

// Shapes (fixed): B=64, N=4, P=128, d=h=256, totP=512, feat=131072
#define P_    128
#define H_    256
#define FEAT_ 131072

// ---------------------------------------------------------------------------
// Fused sim + deg + sym-normalize, reading RAW x (normalization factorized:
// dot(xn_p,xn_q) = G[pq]*inv_p*inv_q, ||x_p||^2 = G[pp]). One block per blk.
// (R10-verified form.)
// ---------------------------------------------------------------------------
__global__ __launch_bounds__(256) void k_simfused(
    const float* __restrict__ x, const float* __restrict__ mask,
    float* __restrict__ An) {
  __shared__ float Xs[16][128];      // [k][row], chunk of K
  __shared__ float red[128][17];     // row partial sums
  __shared__ float diag_s[128];
  __shared__ float inv_s[128];
  __shared__ float dinv_s[128];
  const int blk = blockIdx.x;
  const int t = threadIdx.x;
  const int tp = t >> 4, tq = t & 15;   // rows tp*8..+7, cols tq*8..+7
  const float* Xb = x + (size_t)blk * (128 * 256);

  float v[8][8];
  #pragma unroll
  for (int i = 0; i < 8; ++i)
    #pragma unroll
    for (int j = 0; j < 8; ++j) v[i][j] = 0.f;

  for (int kc = 0; kc < 16; ++kc) {
    __syncthreads();
    #pragma unroll
    for (int l = 0; l < 2; ++l) {
      const int f = t + 256 * l;
      const int row = f >> 2, k4 = (f & 3) * 4;
      const float4 x4 = *(const float4*)(Xb + (size_t)row * 256 + kc * 16 + k4);
      Xs[k4 + 0][row] = x4.x;
      Xs[k4 + 1][row] = x4.y;
      Xs[k4 + 2][row] = x4.z;
      Xs[k4 + 3][row] = x4.w;
    }
    __syncthreads();
    #pragma unroll
    for (int k = 0; k < 16; ++k) {
      const float4 a0 = *(const float4*)&Xs[k][tp * 8];
      const float4 a1 = *(const float4*)&Xs[k][tp * 8 + 4];
      const float4 b0 = *(const float4*)&Xs[k][tq * 8];
      const float4 b1 = *(const float4*)&Xs[k][tq * 8 + 4];
      const float a[8] = {a0.x, a0.y, a0.z, a0.w, a1.x, a1.y, a1.z, a1.w};
      const float b[8] = {b0.x, b0.y, b0.z, b0.w, b1.x, b1.y, b1.z, b1.w};
      #pragma unroll
      for (int i = 0; i < 8; ++i)
        #pragma unroll
        for (int j = 0; j < 8; ++j) v[i][j] += a[i] * b[j];
    }
  }

  // diagonal -> row norms -> inverse norms (matches x / max(||x||, 1e-12))
  if (tp == tq) {
    #pragma unroll
    for (int i = 0; i < 8; ++i) diag_s[tp * 8 + i] = v[i][i];
  }
  __syncthreads();
  if (t < 128) inv_s[t] = 1.0f / fmaxf(sqrtf(diag_s[t]), 1e-12f);
  __syncthreads();

  float ivq[8];
  #pragma unroll
  for (int j = 0; j < 8; ++j) ivq[j] = inv_s[tq * 8 + j];

  #pragma unroll
  for (int i = 0; i < 8; ++i) {
    const int r = tp * 8 + i;
    const float ivp = inv_s[r];
    const float4 m0 = *(const float4*)(mask + r * 128 + tq * 8);
    const float4 m1 = *(const float4*)(mask + r * 128 + tq * 8 + 4);
    const float mm[8] = {m0.x, m0.y, m0.z, m0.w, m1.x, m1.y, m1.z, m1.w};
    float s = 0.f;
    #pragma unroll
    for (int j = 0; j < 8; ++j) {
      const int c = tq * 8 + j;
      const float vv = (r == c) ? 0.0f
                                : (v[i][j] * ivp * ivq[j] + 1.0f) * 0.5f * mm[j];
      v[i][j] = vv;
      s += vv;
    }
    red[r][tq] = s;
  }
  __syncthreads();
  if (t < 128) {
    float sm = 0.f;
    #pragma unroll
    for (int u = 0; u < 16; ++u) sm += red[t][u];
    const float deg = 1.0f + sm;
    dinv_s[t] = (deg > 0.0f) ? rsqrtf(fmaxf(deg, 1e-12f)) : 0.0f;
  }
  __syncthreads();

  float dq[8];
  #pragma unroll
  for (int j = 0; j < 8; ++j) dq[j] = dinv_s[tq * 8 + j];
  float* Ab = An + (size_t)blk * 16384;
  #pragma unroll
  for (int i = 0; i < 8; ++i) {
    const int r = tp * 8 + i;
    const float dp = dinv_s[r];
    float o[8];
    #pragma unroll
    for (int j = 0; j < 8; ++j) {
      const int c = tq * 8 + j;
      o[j] = (r == c) ? dp * dq[j] : v[i][j] * dp * dq[j];
    }
    *(float4*)(Ab + (size_t)r * 128 + tq * 8)     = make_float4(o[0], o[1], o[2], o[3]);
    *(float4*)(Ab + (size_t)r * 128 + tq * 8 + 4) = make_float4(o[4], o[5], o[6], o[7]);
  }
}

// ---------------------------------------------------------------------------
// Tiled GEMM (layer 1): out[32768][256] = A @ W + bias.
// 128x128 tile, grid (256,2), 256 thr, 8x8/thread. LDS padded [16][132]:
// A-frag reads broadcast (4 addrs/wave), W-frag reads 16B-stride (2-way,
// free), A-stage scalar writes 2-way. Halves LDS instr/FLOP vs 4x8 form.
// Bias-first + ascending-k FMA: per-element math identical to prior rounds.
// ---------------------------------------------------------------------------
__global__ __launch_bounds__(256) void k_gemm_t(
    const float* __restrict__ A, const float* __restrict__ W,
    const float* __restrict__ bias, float* __restrict__ out) {
  __shared__ float As[16][132];   // [k][row], pad 132 (stride 528B, 16B-align)
  __shared__ float Ws[16][132];   // [k][col]
  const int rb = blockIdx.x, cb = blockIdx.y;
  const int t = threadIdx.x, tp = t >> 4, tq = t & 15;
  const int m0 = rb * 128, c0 = cb * 128;

  float acc[8][8];
  #pragma unroll
  for (int j = 0; j < 8; ++j) {
    const int cj = (j < 4) ? (tq * 4 + j) : (64 + tq * 4 + (j - 4));
    const float bj = bias[c0 + cj];
    #pragma unroll
    for (int i = 0; i < 8; ++i) acc[i][j] = bj;
  }

  for (int kc = 0; kc < 16; ++kc) {
    __syncthreads();
    #pragma unroll
    for (int l = 0; l < 2; ++l) {   // stage A tile: 128 rows x 16 k
      const int f = t + 256 * l;
      const int row = f >> 2, k4 = (f & 3) * 4;
      const float4 a4 = *(const float4*)(A + (size_t)(m0 + row) * 256 + kc * 16 + k4);
      As[k4 + 0][row] = a4.x;
      As[k4 + 1][row] = a4.y;
      As[k4 + 2][row] = a4.z;
      As[k4 + 3][row] = a4.w;
    }
    #pragma unroll
    for (int l = 0; l < 2; ++l) {   // stage W tile: 16 k x 128 cols
      const int f = t + 256 * l;
      const int k = f >> 5, c4 = (f & 31) * 4;
      *(float4*)&Ws[k][c4] =
          *(const float4*)(W + (size_t)(kc * 16 + k) * 256 + c0 + c4);
    }
    __syncthreads();
    #pragma unroll
    for (int k = 0; k < 16; ++k) {
      const float4 a0 = *(const float4*)&As[k][tp * 4];
      const float4 a1 = *(const float4*)&As[k][64 + tp * 4];
      const float4 w0 = *(const float4*)&Ws[k][tq * 4];
      const float4 w1 = *(const float4*)&Ws[k][64 + tq * 4];
      const float a[8] = {a0.x, a0.y, a0.z, a0.w, a1.x, a1.y, a1.z, a1.w};
      const float w[8] = {w0.x, w0.y, w0.z, w0.w, w1.x, w1.y, w1.z, w1.w};
      #pragma unroll
      for (int i = 0; i < 8; ++i)
        #pragma unroll
        for (int j = 0; j < 8; ++j) acc[i][j] += a[i] * w[j];
    }
  }

  #pragma unroll
  for (int i = 0; i < 8; ++i) {
    const int ri = (i < 4) ? (tp * 4 + i) : (64 + tp * 4 + (i - 4));
    float* orow = out + (size_t)(m0 + ri) * 256 + c0;
    *(float4*)(orow + tq * 4)      = make_float4(acc[i][0], acc[i][1], acc[i][2], acc[i][3]);
    *(float4*)(orow + 64 + tq * 4) = make_float4(acc[i][4], acc[i][5], acc[i][6], acc[i][7]);
  }
}

// ---------------------------------------------------------------------------
// Tiled GEMM (layer 2), same 128x128 8x8 structure, fused BN+ReLU on the A
// operand at staging time. scsh: [0..255]=sc, [256..511]=sh; channel = k.
// ---------------------------------------------------------------------------
__global__ __launch_bounds__(256) void k_gemmbn_t(
    const float* __restrict__ A, const float* __restrict__ scsh,
    const float* __restrict__ W, const float* __restrict__ bias,
    float* __restrict__ out) {
  __shared__ float As[16][132];
  __shared__ float Ws[16][132];
  const int rb = blockIdx.x, cb = blockIdx.y;
  const int t = threadIdx.x, tp = t >> 4, tq = t & 15;
  const int m0 = rb * 128, c0 = cb * 128;

  float acc[8][8];
  #pragma unroll
  for (int j = 0; j < 8; ++j) {
    const int cj = (j < 4) ? (tq * 4 + j) : (64 + tq * 4 + (j - 4));
    const float bj = bias[c0 + cj];
    #pragma unroll
    for (int i = 0; i < 8; ++i) acc[i][j] = bj;
  }

  for (int kc = 0; kc < 16; ++kc) {
    __syncthreads();
    #pragma unroll
    for (int l = 0; l < 2; ++l) {   // stage A tile with BN+ReLU (chan = k)
      const int f = t + 256 * l;
      const int row = f >> 2, k4 = (f & 3) * 4;
      const int col = kc * 16 + k4;
      const float4 a4 = *(const float4*)(A + (size_t)(m0 + row) * 256 + col);
      const float4 sc = *(const float4*)(scsh + col);
      const float4 sh = *(const float4*)(scsh + 256 + col);
      As[k4 + 0][row] = fmaxf(a4.x * sc.x + sh.x, 0.0f);
      As[k4 + 1][row] = fmaxf(a4.y * sc.y + sh.y, 0.0f);
      As[k4 + 2][row] = fmaxf(a4.z * sc.z + sh.z, 0.0f);
      As[k4 + 3][row] = fmaxf(a4.w * sc.w + sh.w, 0.0f);
    }
    #pragma unroll
    for (int l = 0; l < 2; ++l) {
      const int f = t + 256 * l;
      const int k = f >> 5, c4 = (f & 31) * 4;
      *(float4*)&Ws[k][c4] =
          *(const float4*)(W + (size_t)(kc * 16 + k) * 256 + c0 + c4);
    }
    __syncthreads();
    #pragma unroll
    for (int k = 0; k < 16; ++k) {
      const float4 a0 = *(const float4*)&As[k][tp * 4];
      const float4 a1 = *(const float4*)&As[k][64 + tp * 4];
      const float4 w0 = *(const float4*)&Ws[k][tq * 4];
      const float4 w1 = *(const float4*)&Ws[k][64 + tq * 4];
      const float a[8] = {a0.x, a0.y, a0.z, a0.w, a1.x, a1.y, a1.z, a1.w};
      const float w[8] = {w0.x, w0.y, w0.z, w0.w, w1.x, w1.y, w1.z, w1.w};
      #pragma unroll
      for (int i = 0; i < 8; ++i)
        #pragma unroll
        for (int j = 0; j < 8; ++j) acc[i][j] += a[i] * w[j];
    }
  }

  #pragma unroll
  for (int i = 0; i < 8; ++i) {
    const int ri = (i < 4) ? (tp * 4 + i) : (64 + tp * 4 + (i - 4));
    float* orow = out + (size_t)(m0 + ri) * 256 + c0;
    *(float4*)(orow + tq * 4)      = make_float4(acc[i][0], acc[i][1], acc[i][2], acc[i][3]);
    *(float4*)(orow + 64 + tq * 4) = make_float4(acc[i][4], acc[i][5], acc[i][6], acc[i][7]);
  }
}

// ---------------------------------------------------------------------------
// Tiled bmm + fused BN-stat partials. 128x128 tile, 8x8/thread, grid (256,2).
// K=128 (8 chunks). Stats: per-block per-col sum/sumsq over 128 rows ->
// part[(blk*2+cb)*256 + {c | 128+c}]. Deterministic fixed order.
// ---------------------------------------------------------------------------
__global__ __launch_bounds__(256) void k_bmmst(
    const float* __restrict__ An, const float* __restrict__ XW,
    float* __restrict__ out, float* __restrict__ part) {
  __shared__ float As[16][132];   // [q][p]
  __shared__ float Ws[16][132];   // [q][c]
  __shared__ float rs[16][128];
  __shared__ float rq[16][128];
  const int blk = blockIdx.x, cb = blockIdx.y;
  const int t = threadIdx.x, tp = t >> 4, tq = t & 15;
  const float* Ab = An + (size_t)blk * 16384;        // [128][128]
  const float* Xb = XW + (size_t)blk * (128 * 256);  // [128][256]

  float acc[8][8];
  #pragma unroll
  for (int i = 0; i < 8; ++i)
    #pragma unroll
    for (int j = 0; j < 8; ++j) acc[i][j] = 0.f;

  for (int kc = 0; kc < 8; ++kc) {     // K=128, ascending q
    __syncthreads();
    #pragma unroll
    for (int l = 0; l < 2; ++l) {      // stage An tile: 128 p x 16 q
      const int f = t + 256 * l;
      const int row = f >> 2, k4 = (f & 3) * 4;
      const float4 a4 = *(const float4*)(Ab + (size_t)row * 128 + kc * 16 + k4);
      As[k4 + 0][row] = a4.x;
      As[k4 + 1][row] = a4.y;
      As[k4 + 2][row] = a4.z;
      As[k4 + 3][row] = a4.w;
    }
    #pragma unroll
    for (int l = 0; l < 2; ++l) {      // stage XW tile: 16 q x 128 c
      const int f = t + 256 * l;
      const int k = f >> 5, c4 = (f & 31) * 4;
      *(float4*)&Ws[k][c4] =
          *(const float4*)(Xb + (size_t)(kc * 16 + k) * 256 + cb * 128 + c4);
    }
    __syncthreads();
    #pragma unroll
    for (int k = 0; k < 16; ++k) {
      const float4 a0 = *(const float4*)&As[k][tp * 4];
      const float4 a1 = *(const float4*)&As[k][64 + tp * 4];
      const float4 w0 = *(const float4*)&Ws[k][tq * 4];
      const float4 w1 = *(const float4*)&Ws[k][64 + tq * 4];
      const float a[8] = {a0.x, a0.y, a0.z, a0.w, a1.x, a1.y, a1.z, a1.w};
      const float w[8] = {w0.x, w0.y, w0.z, w0.w, w1.x, w1.y, w1.z, w1.w};
      #pragma unroll
      for (int i = 0; i < 8; ++i)
        #pragma unroll
        for (int j = 0; j < 8; ++j) acc[i][j] += a[i] * w[j];
    }
  }

  // stats: per-thread col partial over 8 rows -> LDS -> 128-thread final
  #pragma unroll
  for (int j = 0; j < 8; ++j) {
    const int col = (j < 4) ? (tq * 4 + j) : (64 + tq * 4 + (j - 4));
    float cs = 0.f, cq = 0.f;
    #pragma unroll
    for (int i = 0; i < 8; ++i) { cs += acc[i][j]; cq += acc[i][j] * acc[i][j]; }
    rs[tp][col] = cs;
    rq[tp][col] = cq;
  }
  __syncthreads();
  if (t < 128) {
    float s = 0.f, q = 0.f;
    #pragma unroll
    for (int u = 0; u < 16; ++u) { s += rs[u][t]; q += rq[u][t]; }
    const int base = (blk * 2 + cb) * 256;
    part[base + t]       = s;
    part[base + 128 + t] = q;
  }

  #pragma unroll
  for (int i = 0; i < 8; ++i) {
    const int ri = (i < 4) ? (tp * 4 + i) : (64 + tp * 4 + (i - 4));
    float* orow = out + (size_t)(blk * 128 + ri) * 256 + cb * 128;
    *(float4*)(orow + tq * 4)      = make_float4(acc[i][0], acc[i][1], acc[i][2], acc[i][3]);
    *(float4*)(orow + 64 + tq * 4) = make_float4(acc[i][4], acc[i][5], acc[i][6], acc[i][7]);
  }
}

// ---------------------------------------------------------------------------
// bn final + scsh: block per channel (256 blocks x 256 thr). Thread u sums
// its blk's partial (fixed order), then LDS tree. Deterministic.
// part layout from k_bmmst: (blk*2 + cb)*256 + {lc | 128+lc}, lc=c&127.
// ---------------------------------------------------------------------------
__global__ __launch_bounds__(256) void k_bnscsh(
    const float* __restrict__ part, const float* __restrict__ g,
    const float* __restrict__ be, float* __restrict__ scsh) {
  __shared__ float ss[256], qq[256];
  const int c = blockIdx.x;
  const int cb = c >> 7, lc = c & 127;
  const int u = threadIdx.x;           // = blk
  const float* pb = part + (size_t)(u * 2 + cb) * 256;
  ss[u] = pb[lc];
  qq[u] = pb[128 + lc];
  __syncthreads();
  for (int st = 128; st; st >>= 1) {
    if (u < st) { ss[u] += ss[u + st]; qq[u] += qq[u + st]; }
    __syncthreads();
  }
  if (u == 0) {
    const float m = ss[0] * (1.0f / 32768.0f);
    const float var = qq[0] * (1.0f / 32768.0f) - m * m;
    const float sc = g[c] * rsqrtf(var + 1e-5f);
    scsh[c] = sc;
    scsh[256 + c] = be[c] - m * sc;
  }
}

// ---------------------------------------------------------------------------
// head split-K GEMM v3: 1024 blocks (K-chunk 128) x 256 thr. Graph chunk
// staged in LDS with BN+ReLU applied once. Partials -> part (1024 x 8192).
// ---------------------------------------------------------------------------
__global__ __launch_bounds__(256) void k_headgemm_v3(
    const float* __restrict__ pre2, const float* __restrict__ scsh,
    const float* __restrict__ Wm1, float* __restrict__ part) {
  __shared__ float graphS[64][128];   // 32 KB
  const int t = threadIdx.x;
  const int bid = blockIdx.x;
  const int k0 = bid * 128;
  const int cbase = k0 & 255;

  #pragma unroll
  for (int l = 0; l < 8; ++l) {
    const int f = t + 256 * l;
    const int row = f >> 5, c4 = (f & 31) * 4;
    const float4 p = *(const float4*)(pre2 + (size_t)row * FEAT_ + k0 + c4);
    const float4 sc = *(const float4*)(scsh + cbase + c4);
    const float4 sh = *(const float4*)(scsh + 256 + cbase + c4);
    graphS[row][c4 + 0] = fmaxf(p.x * sc.x + sh.x, 0.0f);
    graphS[row][c4 + 1] = fmaxf(p.y * sc.y + sh.y, 0.0f);
    graphS[row][c4 + 2] = fmaxf(p.z * sc.z + sh.z, 0.0f);
    graphS[row][c4 + 3] = fmaxf(p.w * sc.w + sh.w, 0.0f);
  }
  __syncthreads();

  const int hg = t & 31;
  const int bg = t >> 5;
  float acc[8][4];
  #pragma unroll
  for (int i = 0; i < 8; ++i)
    #pragma unroll
    for (int j = 0; j < 4; ++j) acc[i][j] = 0.f;

  #pragma unroll 2
  for (int kk = 0; kk < 128; kk += 4) {
    const int k = k0 + kk;
    const float4 w0 = *(const float4*)(Wm1 + (size_t)(k + 0) * 128 + hg * 4);
    const float4 w1 = *(const float4*)(Wm1 + (size_t)(k + 1) * 128 + hg * 4);
    const float4 w2 = *(const float4*)(Wm1 + (size_t)(k + 2) * 128 + hg * 4);
    const float4 w3 = *(const float4*)(Wm1 + (size_t)(k + 3) * 128 + hg * 4);
    #pragma unroll
    for (int i = 0; i < 8; ++i) {
      const float4 a = *(const float4*)&graphS[bg * 8 + i][kk];
      acc[i][0] += a.x * w0.x; acc[i][1] += a.x * w0.y;
      acc[i][2] += a.x * w0.z; acc[i][3] += a.x * w0.w;
      acc[i][0] += a.y * w1.x; acc[i][1] += a.y * w1.y;
      acc[i][2] += a.y * w1.z; acc[i][3] += a.y * w1.w;
      acc[i][0] += a.z * w2.x; acc[i][1] += a.z * w2.y;
      acc[i][2] += a.z * w2.z; acc[i][3] += a.z * w2.w;
      acc[i][0] += a.w * w3.x; acc[i][1] += a.w * w3.y;
      acc[i][2] += a.w * w3.z; acc[i][3] += a.w * w3.w;
    }
  }

  float* pb = part + (size_t)bid * 8192;
  #pragma unroll
  for (int i = 0; i < 8; ++i)
    *(float4*)(pb + (bg * 8 + i) * 128 + hg * 4) =
        make_float4(acc[i][0], acc[i][1], acc[i][2], acc[i][3]);
}

// ---------------------------------------------------------------------------
// head reduce stage A: part2[jg][o] = sum of 128 consecutive partials.
// ---------------------------------------------------------------------------
__global__ __launch_bounds__(256) void k_headredA(
    const float* __restrict__ part, float* __restrict__ part2) {
  const int o = blockIdx.x * 256 + threadIdx.x;
  const int jg = blockIdx.y;
  const float* base = part + (size_t)jg * 128 * 8192;
  float s = 0.f;
  for (int j = 0; j < 128; ++j) s += base[(size_t)j * 8192 + o];
  part2[(size_t)jg * 8192 + o] = s;
}

// ---------------------------------------------------------------------------
// Fused head tail: z1 reduce -> BN1+ReLU -> mm2 -> BN2+ReLU -> out.
// ONE block, 256 threads, everything in LDS. (R10-verified form.)
// ---------------------------------------------------------------------------
__global__ __launch_bounds__(256) void k_headtail(
    const float* __restrict__ part2,
    const float* __restrict__ gm1, const float* __restrict__ bem1,
    const float* __restrict__ Wm2,
    const float* __restrict__ gm2, const float* __restrict__ bem2,
    const float* __restrict__ Wm3, const float* __restrict__ bm3,
    float* __restrict__ out) {
  __shared__ float zs[8192];     // z1 / zr1 (64x128)
  __shared__ float wm2s[8192];   // Wm2 (128x64)
  __shared__ float zb2[4096];    // z2 / zr2 (64x64)
  __shared__ float sc1[128], sh1[128], sc2[64], sh2[64];
  const int t = threadIdx.x;

  // z1[o] = sum_{jg<8} part2[jg][o]
  for (int o = t; o < 8192; o += 256) {
    float s = 0.f;
    #pragma unroll
    for (int jg = 0; jg < 8; ++jg) s += part2[(size_t)jg * 8192 + o];
    zs[o] = s;
  }
  for (int o = t; o < 8192; o += 256) wm2s[o] = Wm2[o];
  __syncthreads();

  // BN1 stats over batch (64) per feature
  if (t < 128) {
    float s = 0.f, q = 0.f;
    for (int b = 0; b < 64; ++b) { const float v = zs[b * 128 + t]; s += v; q += v * v; }
    const float m = s * (1.0f / 64.0f);
    const float var = q * (1.0f / 64.0f) - m * m;
    const float sc = gm1[t] * rsqrtf(var + 1e-5f);
    sc1[t] = sc; sh1[t] = bem1[t] - m * sc;
  }
  __syncthreads();
  for (int o = t; o < 8192; o += 256)
    zs[o] = fmaxf(zs[o] * sc1[o & 127] + sh1[o & 127], 0.0f);
  __syncthreads();

  // mm2: z2[b][j] = sum_k zr1[b][k]*Wm2[k][j]; 4x4 register tile per thread
  {
    const int bq = t >> 4, jq = t & 15;    // b-quad, j-quad
    float acc[4][4];
    #pragma unroll
    for (int bi = 0; bi < 4; ++bi)
      #pragma unroll
      for (int ji = 0; ji < 4; ++ji) acc[bi][ji] = 0.f;
    for (int k = 0; k < 128; ++k) {        // ascending k, one FMA per k
      const float4 w4 = *(const float4*)&wm2s[k * 64 + jq * 4];
      const float wv[4] = {w4.x, w4.y, w4.z, w4.w};
      #pragma unroll
      for (int bi = 0; bi < 4; ++bi) {
        const float zv = zs[(bq * 4 + bi) * 128 + k];
        #pragma unroll
        for (int ji = 0; ji < 4; ++ji) acc[bi][ji] += zv * wv[ji];
      }
    }
    #pragma unroll
    for (int bi = 0; bi < 4; ++bi)
      #pragma unroll
      for (int ji = 0; ji < 4; ++ji)
        zb2[(bq * 4 + bi) * 64 + jq * 4 + ji] = acc[bi][ji];
  }
  __syncthreads();

  // BN2 stats over batch (64) per feature
  if (t < 64) {
    float s = 0.f, q = 0.f;
    for (int b = 0; b < 64; ++b) { const float v = zb2[b * 64 + t]; s += v; q += v * v; }
    const float m = s * (1.0f / 64.0f);
    const float var = q * (1.0f / 64.0f) - m * m;
    const float sc = gm2[t] * rsqrtf(var + 1e-5f);
    sc2[t] = sc; sh2[t] = bem2[t] - m * sc;
  }
  __syncthreads();
  for (int idx = t; idx < 4096; idx += 256)
    zb2[idx] = fmaxf(zb2[idx] * sc2[idx & 63] + sh2[idx & 63], 0.0f);
  __syncthreads();

  // out[b][c] = bm3[c] + sum_k zr2[b][k]*Wm3[k][c]
  if (t < 128) {
    const int b = t >> 1, c = t & 1;
    float s = bm3[c];
    for (int k = 0; k < 64; ++k) s += zb2[b * 64 + k] * Wm3[k * 2 + c];
    out[t] = s;
  }
}

// ---------------------------------------------------------------------------
extern "C" void kernel_launch(void* const* d_in, const int* in_sizes, int n_in,
                              void* d_out, int out_size, void* d_ws, size_t ws_size,
                              hipStream_t stream) {
  (void)in_sizes; (void)n_in; (void)out_size; (void)ws_size;
  const float* x    = (const float*)d_in[0];
  const float* mask = (const float*)d_in[1];
  const float* W1   = (const float*)d_in[2];
  const float* b1   = (const float*)d_in[3];
  const float* g1   = (const float*)d_in[4];
  const float* be1  = (const float*)d_in[5];
  const float* W2   = (const float*)d_in[6];
  const float* b2   = (const float*)d_in[7];
  const float* g2   = (const float*)d_in[8];
  const float* be2  = (const float*)d_in[9];
  const float* Wm1  = (const float*)d_in[10];
  // d_in[11] = bm1 (zeros; cancels under BN)
  const float* gm1  = (const float*)d_in[12];
  const float* bem1 = (const float*)d_in[13];
  const float* Wm2  = (const float*)d_in[14];
  // d_in[15] = bm2 (zeros; cancels under BN)
  const float* gm2  = (const float*)d_in[16];
  const float* bem2 = (const float*)d_in[17];
  const float* Wm3  = (const float*)d_in[18];
  const float* bm3  = (const float*)d_in[19];

  // workspace (floats), same extent as verified previously (117.67 MB)
  float* ws   = (float*)d_ws;
  float* T1   = ws;                 // 8,388,608 : bn partials
  float* An   = T1 + 8388608;       // 4,194,304 : An -> head part2
  float* T2   = An + 4194304;       // 8,388,608 : XW1 -> XW2 -> head partials
  float* T3   = T2 + 8388608;       // 8,388,608 : pre1 -> pre2
  float* z1   = T3 + 8388608;       // 8,192 (unused now)
  float* dinv = z1 + 8192;          // 32,768 : scsh1 at +0, scsh2 at +512
  (void)z1;

  float* scsh1 = dinv;
  float* scsh2 = dinv + 512;

  // edges / An (fused: Gram + norm-factorized sim + deg + normalize)
  k_simfused<<<256, 256, 0, stream>>>(x, mask, An);

  // layer 1: pre1 = An @ (x@W1+b1); stats fused into bmm
  k_gemm_t<<<dim3(256, 2), 256, 0, stream>>>(x, W1, b1, T2);
  k_bmmst<<<dim3(256, 2), 256, 0, stream>>>(An, T2, T3, T1);
  k_bnscsh<<<256, 256, 0, stream>>>(T1, g1, be1, scsh1);

  // layer 2: pre2 = An @ (relu(bn(pre1))@W2+b2); bn fused into A-staging
  k_gemmbn_t<<<dim3(256, 2), 256, 0, stream>>>(T3, scsh1, W2, b2, T2);
  k_bmmst<<<dim3(256, 2), 256, 0, stream>>>(An, T2, T3, T1);
  k_bnscsh<<<256, 256, 0, stream>>>(T1, g2, be2, scsh2);

  // head: z1 = relu(bn(pre2)) @ Wm1, split-K + reduce + fused tail
  k_headgemm_v3<<<1024, 256, 0, stream>>>(T3, scsh2, Wm1, T2);
  k_headredA<<<dim3(32, 8), 256, 0, stream>>>(T2, An);
  k_headtail<<<1, 256, 0, stream>>>(An, gm1, bem1, Wm2, gm2, bem2,
                                    Wm3, bm3, (float*)d_out);
}